// Round 17
// baseline (268.842 us; speedup 1.0000x reference)
//
#include <hip/hip_runtime.h>

#define EPS 1e-5f
typedef unsigned char u8;
typedef unsigned short u16;
typedef unsigned int u32;
typedef float f32x2 __attribute__((ext_vector_type(2)));
typedef float f32x4 __attribute__((ext_vector_type(4)));
typedef short bf16x8 __attribute__((ext_vector_type(8)));
typedef unsigned int u32x2 __attribute__((ext_vector_type(2)));

__device__ __forceinline__ float bf2f(u16 h){
  return __uint_as_float(((u32)h) << 16);
}
__device__ __forceinline__ u16 f2bf(float f){
  u32 u = __float_as_uint(f);
  u += 0x7fffu + ((u >> 16) & 1u);
  return (u16)(u >> 16);
}
__device__ __forceinline__ u32 pk2(float lo, float hi){
  return ((u32)f2bf(hi) << 16) | (u32)f2bf(lo);
}
union BF8 { bf16x8 v; u32 u[4]; };

// fp8x8 (packed in u32x2) -> bf16x8 via HW cvt
__device__ __forceinline__ bf16x8 fp8_to_bf16x8(u32x2 a){
  f32x2 f01 = __builtin_amdgcn_cvt_pk_f32_fp8(a.x, false);
  f32x2 f23 = __builtin_amdgcn_cvt_pk_f32_fp8(a.x, true);
  f32x2 f45 = __builtin_amdgcn_cvt_pk_f32_fp8(a.y, false);
  f32x2 f67 = __builtin_amdgcn_cvt_pk_f32_fp8(a.y, true);
  BF8 r;
  r.u[0] = pk2(f01.x, f01.y); r.u[1] = pk2(f23.x, f23.y);
  r.u[2] = pk2(f45.x, f45.y); r.u[3] = pk2(f67.x, f67.y);
  return r.v;
}

// ---------------------------------------------------------------------------
// k_prep1: GN(x)->normed, GN(normed)->xr, gap. grid(8,32).
// ---------------------------------------------------------------------------
__global__ __launch_bounds__(256) void k_prep1(
    const float* __restrict__ x, const float* __restrict__ gn_g, const float* __restrict__ gn_b,
    const float* __restrict__ ra_g, const float* __restrict__ ra_b,
    float* __restrict__ normed, float* __restrict__ xr, float* __restrict__ gap)
{
  int ch = blockIdx.x, b = blockIdx.y;
  int c0 = ch * 32;
  __shared__ float xs[1568], ns[1568];
  const float* xb = x + ((size_t)b * 256 + c0) * 49;
  for (int i = threadIdx.x; i < 1568; i += 256) xs[i] = xb[i];
  __syncthreads();
  int wv = threadIdx.x >> 6, lane = threadIdx.x & 63;
  const float* gsrc = xs + wv * 392;
  float* ndst = ns + wv * 392;
  float s = 0.f, ss = 0.f;
  for (int i = lane; i < 392; i += 64){ float v = gsrc[i]; s += v; ss += v * v; }
  for (int off = 32; off; off >>= 1){ s += __shfl_down(s, off); ss += __shfl_down(ss, off); }
  s = __shfl(s, 0); ss = __shfl(ss, 0);
  float m = s / 392.f, rs = rsqrtf(ss / 392.f - m * m + EPS);
  for (int i = lane; i < 392; i += 64){
    int c = c0 + wv * 8 + i / 49;
    ndst[i] = (gsrc[i] - m) * rs * gn_g[c] + gn_b[c];
  }
  __syncthreads();
  float* nb = normed + ((size_t)b * 256 + c0) * 49;
  for (int i = threadIdx.x; i < 1568; i += 256) nb[i] = ns[i];
  if (threadIdx.x < 32){
    float g2 = 0.f; const float* rp = ns + threadIdx.x * 49;
    for (int p = 0; p < 49; p++) g2 += rp[p];
    gap[(size_t)b * 256 + c0 + threadIdx.x] = g2 * (1.f / 49.f);
  }
  s = 0.f; ss = 0.f;
  for (int i = lane; i < 392; i += 64){ float v = ndst[i]; s += v; ss += v * v; }
  for (int off = 32; off; off >>= 1){ s += __shfl_down(s, off); ss += __shfl_down(ss, off); }
  s = __shfl(s, 0); ss = __shfl(ss, 0);
  m = s / 392.f; rs = rsqrtf(ss / 392.f - m * m + EPS);
  float* xrb = xr + ((size_t)b * 256 + c0) * 49;
  for (int i = lane; i < 392; i += 64){
    int c = c0 + wv * 8 + i / 49;
    xrb[wv * 392 + i] = (ndst[i] - m) * rs * ra_g[c] + ra_b[c];
  }
}

// ---------------------------------------------------------------------------
// dev_pos / dev_h1aw  (merged into k_pre2)
// ---------------------------------------------------------------------------
__device__ void dev_pos(
    const float* __restrict__ x, const float* __restrict__ normed,
    const float* __restrict__ gate_w, const float* __restrict__ gate_b,
    float* __restrict__ gates_g, float* __restrict__ lnm_g, float* __restrict__ lnr_g,
    int pc, int b, float* sm)
{
  float* gw = sm;  // 1024
  for (int i = threadIdx.x; i < 1024; i += 256) gw[i] = gate_w[i];
  __syncthreads();
  int wv = threadIdx.x >> 6, lane = threadIdx.x & 63;
  for (int pi = wv; pi < 7; pi += 4){
    int p = pc * 7 + pi;
    const float* nb = normed + (size_t)b * 12544 + p;
    const float* xb = x + (size_t)b * 12544 + p;
    float s = 0.f, ss = 0.f, g0 = 0.f, g1 = 0.f, g2 = 0.f, g3 = 0.f;
    for (int c = lane; c < 256; c += 64){
      float nv = nb[c * 49];
      float xv = xb[c * 49];
      s += nv; ss += nv * nv;
      g0 += xv * gw[c]; g1 += xv * gw[256 + c];
      g2 += xv * gw[512 + c]; g3 += xv * gw[768 + c];
    }
    for (int off = 32; off; off >>= 1){
      s += __shfl_down(s, off); ss += __shfl_down(ss, off);
      g0 += __shfl_down(g0, off); g1 += __shfl_down(g1, off);
      g2 += __shfl_down(g2, off); g3 += __shfl_down(g3, off);
    }
    if (lane == 0){
      float mu = s / 256.f;
      lnm_g[b * 49 + p] = mu;
      lnr_g[b * 49 + p] = rsqrtf(ss / 256.f - mu * mu + EPS);
      g0 += gate_b[0]; g1 += gate_b[1]; g2 += gate_b[2]; g3 += gate_b[3];
      float mx = fmaxf(fmaxf(g0, g1), fmaxf(g2, g3));
      float e0 = __expf(g0 - mx), e1 = __expf(g1 - mx), e2 = __expf(g2 - mx), e3 = __expf(g3 - mx);
      float inv = 1.f / (e0 + e1 + e2 + e3);
      float* gg = gates_g + (size_t)b * 196 + p;
      gg[0] = e0 * inv; gg[49] = e1 * inv; gg[98] = e2 * inv; gg[147] = e3 * inv;
    }
  }
}

__device__ void dev_h1aw(
    const float* __restrict__ normed, const float* __restrict__ sa_w1, const float* __restrict__ sa_b1,
    const float* __restrict__ ap_w1, const float* __restrict__ ap_b1,
    const float* __restrict__ ap_w2, const float* __restrict__ ap_b2,
    const float* __restrict__ gap_g,
    float* __restrict__ h1_g, float* __restrict__ aw_g,
    int xb2, int b, float* sm)
{
  int t = threadIdx.x;
  if (xb2 == 7){
    float* gaps = sm; float* h = sm + 256; float* lg = sm + 384;
    gaps[t] = gap_g[b * 256 + t];
    __syncthreads();
    if (t < 128){
      float s = ap_b1[t];
      const float* wr = ap_w1 + t * 256;
      #pragma unroll 4
      for (int c = 0; c < 256; c++) s += gaps[c] * wr[c];
      h[t] = fmaxf(s, 0.f);
    }
    __syncthreads();
    if (t < 16){
      float s = ap_b2[t];
      const float* wr = ap_w2 + t * 128;
      #pragma unroll 4
      for (int o = 0; o < 128; o++) s += h[o] * wr[o];
      lg[t] = s;
    }
    __syncthreads();
    if (t == 0){
      float mx = -1e30f;
      for (int k = 0; k < 16; k++) mx = fmaxf(mx, lg[k]);
      float e[16], smm = 0.f;
      for (int k = 0; k < 16; k++){ e[k] = __expf(lg[k] - mx); smm += e[k]; }
      float inv = 1.f / smm;
      for (int k = 0; k < 16; k++) aw_g[b * 16 + k] = e[k] * inv;
    }
    return;
  }
  float* w1t = sm;            // 8448
  float* ns2 = sm + 8448;     // 1792
  int p0 = xb2 * 7;
  for (int i = t; i < 8192; i += 256){
    int o = i >> 8, c = i & 255;
    w1t[c * 33 + o] = sa_w1[i];
  }
  for (int i = t; i < 1792; i += 256){
    int c = i / 7, pl = i - c * 7;
    ns2[i] = normed[(size_t)b * 12544 + c * 49 + p0 + pl];
  }
  __syncthreads();
  if (t < 224){
    int pl = t >> 5, o = t & 31;
    float s = sa_b1[o];
    #pragma unroll 8
    for (int c = 0; c < 256; c++) s += ns2[c * 7 + pl] * w1t[c * 33 + o];
    h1_g[(size_t)b * 1568 + (p0 + pl) * 32 + o] = fmaxf(s, 0.f);
  }
}

__global__ __launch_bounds__(256) void k_pre2(
    const float* __restrict__ x, const float* __restrict__ normed,
    const float* __restrict__ gate_w, const float* __restrict__ gate_b,
    const float* __restrict__ sa_w1, const float* __restrict__ sa_b1,
    const float* __restrict__ ap_w1, const float* __restrict__ ap_b1,
    const float* __restrict__ ap_w2, const float* __restrict__ ap_b2,
    const float* __restrict__ gap_g,
    float* __restrict__ gates_g, float* __restrict__ lnm_g, float* __restrict__ lnr_g,
    float* __restrict__ h1_g, float* __restrict__ aw_g)
{
  __shared__ float sm[10240];
  int bx = blockIdx.x, b = blockIdx.y;
  if (bx < 7)
    dev_pos(x, normed, gate_w, gate_b, gates_g, lnm_g, lnr_g, bx, b, sm);
  else
    dev_h1aw(normed, sa_w1, sa_b1, ap_w1, ap_b1, ap_w2, ap_b2, gap_g, h1_g, aw_g, bx - 7, b, sm);
}

// ---------------------------------------------------------------------------
// device pieces
// ---------------------------------------------------------------------------
__device__ void dev_spatial(
    const float* __restrict__ normed, const float* __restrict__ h1_g,
    const float* __restrict__ sa_w2, const float* __restrict__ sa_b2,
    const float* __restrict__ sa_g, const float* __restrict__ sa_bb,
    float* __restrict__ spat_g, int gc, int b, float* sm)
{
  float* h1s = sm;           // 1617
  float* w2s = sm + 1617;    // 1024
  int t = threadIdx.x;
  for (int i = t; i < 1568; i += 256){
    int p = i >> 5, o = i & 31;
    h1s[p * 33 + o] = h1_g[(size_t)b * 1568 + i];
  }
  for (int i = t; i < 1024; i += 256) w2s[i] = sa_w2[gc * 1024 + i];
  __syncthreads();
  int wv = t >> 6, lane = t & 63;
  int cg0 = wv * 8;
  const float* nb = normed + (size_t)b * 12544 + (gc * 32 + cg0) * 49;
  float tmp[7];
  float s = 0.f, ss = 0.f;
  #pragma unroll
  for (int j = 0; j < 7; j++){
    int i = lane + 64 * j;
    float v = 0.f;
    if (i < 392){
      int c = i / 49;
      const float* wr = w2s + (cg0 + c) * 32;
      const float* hp = h1s + (i - c * 49) * 33;
      float d = sa_b2[gc * 32 + cg0 + c];
      #pragma unroll
      for (int o = 0; o < 32; o++) d += hp[o] * wr[o];
      v = nb[i] * (1.f + 1.f / (1.f + __expf(-d)));
      s += v; ss += v * v;
    }
    tmp[j] = v;
  }
  for (int off = 32; off; off >>= 1){ s += __shfl_down(s, off); ss += __shfl_down(ss, off); }
  s = __shfl(s, 0); ss = __shfl(ss, 0);
  float m = s / 392.f, rs = rsqrtf(ss / 392.f - m * m + EPS);
  float* sb = spat_g + (size_t)b * 12544 + (gc * 32 + cg0) * 49;
  #pragma unroll
  for (int j = 0; j < 7; j++){
    int i = lane + 64 * j;
    if (i < 392){
      int c = gc * 32 + cg0 + i / 49;
      sb[i] = (tmp[j] - m) * rs * sa_g[c] + sa_bb[c];
    }
  }
}

// weff: fp8 e4m3, pre-scaled x16 (decode side folds 1/16 into xim).
// block bx in [0,1600) covers j = (bx*256+tid)*4; one u32 NT store per batch.
__device__ void dev_weff(
    const float* __restrict__ W, const float* __restrict__ aw, u8* __restrict__ weff, int bx)
{
  const size_t t = ((size_t)bx * 256 + threadIdx.x) * 4;
  float4 A[16];
  #pragma unroll
  for (int k = 0; k < 16; k++) A[k] = *(const float4*)(W + (size_t)k * 1638400 + t);
  #pragma unroll 1
  for (int b = 0; b < 32; b++){
    float s0 = 0.f, s1 = 0.f, s2 = 0.f, s3 = 0.f;
    #pragma unroll
    for (int k = 0; k < 16; k++){
      float a = aw[b * 16 + k];
      s0 += a * A[k].x; s1 += a * A[k].y; s2 += a * A[k].z; s3 += a * A[k].w;
    }
    int pk = __builtin_amdgcn_cvt_pk_fp8_f32(s0 * 16.f, s1 * 16.f, 0, false);
    pk = __builtin_amdgcn_cvt_pk_fp8_f32(s2 * 16.f, s3 * 16.f, pk, true);
    __builtin_nontemporal_store((u32)pk, (u32*)(weff + (size_t)b * 1638400 + t));
  }
}

// im2col: xim = bf16(normed/16); zero outside image.
__device__ void dev_im2col(
    const float* __restrict__ normed, u16* __restrict__ xim, int p, int b, float* sm)
{
  u16* row = (u16*)sm;  // 6400 u16
  int ci = threadIdx.x;
  int py = p / 7, px = p - py * 7;
  const float* nb = normed + (size_t)b * 12544 + ci * 49;
  u16* rp = row + ci * 25;
  #pragma unroll
  for (int sy = 0; sy < 5; sy++){
    int iy = py + sy - 2;
    #pragma unroll
    for (int sx = 0; sx < 5; sx++){
      int ix = px + sx - 2;
      float v = (iy >= 0 && iy < 7 && ix >= 0 && ix < 7) ? nb[iy * 7 + ix] * 0.0625f : 0.f;
      rp[sy * 5 + sx] = f2bf(v);
    }
  }
  __syncthreads();
  const u32* rs = (const u32*)row;
  u32* od = (u32*)(xim + (size_t)(b * 49 + p) * 6400);
  for (int i = threadIdx.x; i < 3200; i += 256) od[i] = rs[i];
}

// mfma_gemm_dev: per-wave 32m x 16p tile; optional LN-fused act, optional
// 8-way partial-sum act (part8 != nullptr reads Sum_kp partial instead).
__device__ __forceinline__ void mfma_gemm_dev(
    const float* __restrict__ W, const float* __restrict__ bias,
    const float* __restrict__ act, const float* __restrict__ res,
    float* __restrict__ out, int M, int K, int m0blk, int p0, int b,
    const float* __restrict__ lnm, const float* __restrict__ lnr,
    const float* __restrict__ lng, const float* __restrict__ lnb,
    const float* __restrict__ part8 = nullptr)
{
  int wv = threadIdx.x >> 6, lane = threadIdx.x & 63;
  int lo = lane & 15, hi = lane >> 4;
  int m0 = m0blk + wv * 32;
  int p = p0 + lo;
  bool pok = p < 49;
  const float* ab = act + (size_t)b * K * 49;
  float lm = 0.f, lr = 0.f;
  if (lng && pok){ lm = lnm[p]; lr = lnr[p]; }
  f32x4 acc0 = {0.f, 0.f, 0.f, 0.f};
  f32x4 acc1 = {0.f, 0.f, 0.f, 0.f};
  const float* wr0 = W + (size_t)(m0 + lo) * K + hi * 8;
  const float* wr1 = W + (size_t)(m0 + 16 + lo) * K + hi * 8;
  for (int k0 = 0; k0 < K; k0 += 32){
    int kb = k0 + hi * 8;
    float4 a0lo = *(const float4*)(wr0 + k0);
    float4 a0hi = *(const float4*)(wr0 + k0 + 4);
    float4 a1lo = *(const float4*)(wr1 + k0);
    float4 a1hi = *(const float4*)(wr1 + k0 + 4);
    float bv[8];
    if (pok){
      if (part8){
        const float* pp = part8 + (size_t)b * 12544 + (size_t)kb * 49 + p;
        #pragma unroll
        for (int i = 0; i < 8; i++){
          float s = 0.f;
          #pragma unroll
          for (int kp = 0; kp < 8; kp++) s += pp[(size_t)kp * 401408 + i * 49];
          bv[i] = s;
        }
      } else {
        const float* ap = ab + (size_t)kb * 49 + p;
        #pragma unroll
        for (int i = 0; i < 8; i++) bv[i] = ap[i * 49];
        if (lng){
          #pragma unroll
          for (int i = 0; i < 8; i++) bv[i] = (bv[i] - lm) * lr * lng[kb + i] + lnb[kb + i];
        }
      }
    } else {
      #pragma unroll
      for (int i = 0; i < 8; i++) bv[i] = 0.f;
    }
    BF8 A0, A1, B;
    A0.u[0] = pk2(a0lo.x, a0lo.y); A0.u[1] = pk2(a0lo.z, a0lo.w);
    A0.u[2] = pk2(a0hi.x, a0hi.y); A0.u[3] = pk2(a0hi.z, a0hi.w);
    A1.u[0] = pk2(a1lo.x, a1lo.y); A1.u[1] = pk2(a1lo.z, a1lo.w);
    A1.u[2] = pk2(a1hi.x, a1hi.y); A1.u[3] = pk2(a1hi.z, a1hi.w);
    B.u[0] = pk2(bv[0], bv[1]); B.u[1] = pk2(bv[2], bv[3]);
    B.u[2] = pk2(bv[4], bv[5]); B.u[3] = pk2(bv[6], bv[7]);
    acc0 = __builtin_amdgcn_mfma_f32_16x16x32_bf16(A0.v, B.v, acc0, 0, 0, 0);
    acc1 = __builtin_amdgcn_mfma_f32_16x16x32_bf16(A1.v, B.v, acc1, 0, 0, 0);
  }
  if (pok){
    #pragma unroll
    for (int r = 0; r < 4; r++){
      int m = m0 + hi * 4 + r;
      size_t idx = ((size_t)b * M + m) * 49 + p;
      float v = acc0[r] + (bias ? bias[m] : 0.f);
      if (res) v += res[idx];
      out[idx] = v;
      int m2 = m + 16;
      size_t idx2 = idx + 16 * 49;
      float v2 = acc1[r] + (bias ? bias[m2] : 0.f);
      if (res) v2 += res[idx2];
      out[idx2] = v2;
    }
  }
}

__device__ void dev_conv(
    const u8* __restrict__ weff, const u16* __restrict__ xim, float* __restrict__ partial,
    int bx, int b)
{
  int mblk = bx >> 3, kp = bx & 7;
  int wv = threadIdx.x >> 6, lane = threadIdx.x & 63;
  int lo = lane & 15, hi = lane >> 4;
  int co0 = mblk * 128 + wv * 32;
  const u8* wr0 = weff + (size_t)b * 1638400 + (size_t)(co0 + lo) * 6400 + kp * 800 + hi * 8;
  const u8* wr1 = wr0 + 16 * 6400;
  const u16* xb = xim + (size_t)b * 313600 + (size_t)lo * 6400 + kp * 800 + hi * 8;
  f32x4 acc[2][4];
  #pragma unroll
  for (int mi = 0; mi < 2; mi++)
    #pragma unroll
    for (int pi = 0; pi < 4; pi++) acc[mi][pi] = (f32x4){0.f, 0.f, 0.f, 0.f};
  #pragma unroll 1
  for (int ks = 0; ks < 25; ks++){
    int k0 = ks * 32;
    u32x2 a0p = __builtin_nontemporal_load((const u32x2*)(wr0 + k0));
    u32x2 a1p = __builtin_nontemporal_load((const u32x2*)(wr1 + k0));
    bf16x8 A0 = fp8_to_bf16x8(a0p);
    bf16x8 A1 = fp8_to_bf16x8(a1p);
    bf16x8 B0 = *(const bf16x8*)(xb + k0);
    bf16x8 B1 = *(const bf16x8*)(xb + 16 * 6400 + k0);
    bf16x8 B2 = *(const bf16x8*)(xb + 32 * 6400 + k0);
    bf16x8 B3 = *(const bf16x8*)(xb + 48 * 6400 + k0);
    acc[0][0] = __builtin_amdgcn_mfma_f32_16x16x32_bf16(A0, B0, acc[0][0], 0, 0, 0);
    acc[0][1] = __builtin_amdgcn_mfma_f32_16x16x32_bf16(A0, B1, acc[0][1], 0, 0, 0);
    acc[0][2] = __builtin_amdgcn_mfma_f32_16x16x32_bf16(A0, B2, acc[0][2], 0, 0, 0);
    acc[0][3] = __builtin_amdgcn_mfma_f32_16x16x32_bf16(A0, B3, acc[0][3], 0, 0, 0);
    acc[1][0] = __builtin_amdgcn_mfma_f32_16x16x32_bf16(A1, B0, acc[1][0], 0, 0, 0);
    acc[1][1] = __builtin_amdgcn_mfma_f32_16x16x32_bf16(A1, B1, acc[1][1], 0, 0, 0);
    acc[1][2] = __builtin_amdgcn_mfma_f32_16x16x32_bf16(A1, B2, acc[1][2], 0, 0, 0);
    acc[1][3] = __builtin_amdgcn_mfma_f32_16x16x32_bf16(A1, B3, acc[1][3], 0, 0, 0);
  }
  float* pb = partial + ((size_t)kp * 32 + b) * 12544;
  #pragma unroll
  for (int mi = 0; mi < 2; mi++){
    #pragma unroll
    for (int pi = 0; pi < 4; pi++){
      int p = pi * 16 + lo;
      if (p < 49){
        #pragma unroll
        for (int r = 0; r < 4; r++){
          int co = co0 + mi * 16 + hi * 4 + r;
          pb[co * 49 + p] = acc[mi][pi][r];
        }
      }
    }
  }
}

__device__ __forceinline__ void softmax_rows(float* sc, int tid)
{
  int r = tid >> 2, q = tid & 3;
  if (r < 49){
    float* row = sc + r * 52;
    float mx = -1e30f;
    for (int j = q; j < 49; j += 4) mx = fmaxf(mx, row[j]);
    mx = fmaxf(mx, __shfl_xor(mx, 1));
    mx = fmaxf(mx, __shfl_xor(mx, 2));
    float sm = 0.f;
    for (int j = q; j < 49; j += 4){ float e = __expf(row[j] - mx); row[j] = e; sm += e; }
    sm += __shfl_xor(sm, 1);
    sm += __shfl_xor(sm, 2);
    float inv = 1.f / sm;
    for (int j = q; j < 49; j += 4) row[j] *= inv;
  }
}

__device__ void dev_attn(
    const float* __restrict__ ra_qkv, const float* __restrict__ aa_qkv,
    const float* __restrict__ relpos,
    float* __restrict__ r0, float* __restrict__ ao,
    int xb2, int b, float* sm)
{
  if (xb2 < 8){
    int hd = xb2;
    float* qs = sm; float* ks = sm + 1617; float* vs = sm + 3234; float* sc = sm + 4851;
    const float* base = ra_qkv + (size_t)b * 768 * 49;
    for (int i = threadIdx.x; i < 1568; i += 256){
      int d = i / 49, tok = i - d * 49;
      qs[tok * 33 + d] = base[(hd * 32 + d) * 49 + tok];
      ks[tok * 33 + d] = base[(256 + hd * 32 + d) * 49 + tok];
      vs[tok * 33 + d] = base[(512 + hd * 32 + d) * 49 + tok];
    }
    __syncthreads();
    const float scale = 0.17677669529663687f;
    for (int it = threadIdx.x; it < 2401; it += 256){
      int i = it / 49, j = it - i * 49;
      float s = 0.f;
      #pragma unroll
      for (int d = 0; d < 32; d++) s += qs[i * 33 + d] * ks[j * 33 + d];
      sc[i * 52 + j] = s * scale;
    }
    __syncthreads();
    softmax_rows(sc, threadIdx.x);
    __syncthreads();
    for (int it = threadIdx.x; it < 1568; it += 256){
      int d = it / 49, i = it - d * 49;
      float o = 0.f;
      for (int j = 0; j < 49; j++) o += sc[i * 52 + j] * vs[j * 33 + d];
      r0[((size_t)b * 256 + hd * 32 + d) * 49 + i] = o;
    }
  } else {
    int hd = xb2 - 8;
    float* qs = sm; float* ks = sm + 3185; float* vs = sm + 6370; float* sc = sm + 9555;
    const float* base = aa_qkv + (size_t)b * 1536 * 49;
    for (int i = threadIdx.x; i < 3136; i += 256){
      int d = i / 49, tok = i - d * 49;
      qs[tok * 65 + d] = base[(hd * 64 + d) * 49 + tok];
      ks[tok * 65 + d] = base[(512 + hd * 64 + d) * 49 + tok];
      vs[tok * 65 + d] = base[(1024 + hd * 64 + d) * 49 + tok];
    }
    __syncthreads();
    for (int it = threadIdx.x; it < 2401; it += 256){
      int i = it / 49, j = it - i * 49;
      float s = 0.f;
      #pragma unroll
      for (int d = 0; d < 64; d++) s += qs[i * 65 + d] * ks[j * 65 + d];
      int dy = j / 7 - i / 7 + 6, dx = j % 7 - i % 7 + 6;
      sc[i * 52 + j] = s * 0.125f + relpos[(dy * 13 + dx) * 8 + hd];
    }
    __syncthreads();
    softmax_rows(sc, threadIdx.x);
    __syncthreads();
    for (int it = threadIdx.x; it < 3136; it += 256){
      int d = it / 49, i = it - d * 49;
      float o = 0.f;
      for (int j = 0; j < 49; j++) o += sc[i * 52 + j] * vs[j * 65 + d];
      ao[((size_t)b * 512 + hd * 64 + d) * 49 + i] = o;
    }
  }
}

// ---------------------------------------------------------------------------
// k_mega1: 5472 blocks scrambled (*2003 mod 5472):
// id<1600 weff | <3904 qkv | else im2col
// ---------------------------------------------------------------------------
__global__ __launch_bounds__(256) void k_mega1(
    const float* __restrict__ ad_dir_w, const float* __restrict__ aw, u8* __restrict__ weff,
    const float* __restrict__ ra_w, const float* __restrict__ aa_w,
    const float* __restrict__ xr, const float* __restrict__ normed,
    const float* __restrict__ lnm, const float* __restrict__ lnr,
    const float* __restrict__ ln_g, const float* __restrict__ ln_b,
    float* __restrict__ ra_qkv, float* __restrict__ aa_qkv,
    u16* __restrict__ xim)
{
  __shared__ float sm[3300];
  int id = (int)(((long long)blockIdx.x * 2003) % 5472);
  if (id < 1600){
    dev_weff(ad_dir_w, aw, weff, id);
  } else if (id < 3904){
    int q = id - 1600;
    int bx = q % 72, b = q / 72;
    if (bx < 24){
      int m0 = (bx >> 2) * 128, p0 = (bx & 3) * 16;
      mfma_gemm_dev(ra_w, nullptr, xr, nullptr, ra_qkv, 768, 256, m0, p0, b,
                    nullptr, nullptr, nullptr, nullptr);
    } else {
      int bx2 = bx - 24;
      int m0 = (bx2 >> 2) * 128, p0 = (bx2 & 3) * 16;
      mfma_gemm_dev(aa_w, nullptr, normed, nullptr, aa_qkv, 1536, 256, m0, p0, b,
                    lnm + b * 49, lnr + b * 49, ln_g, ln_b);
    }
  } else {
    int q = id - 3904;
    dev_im2col(normed, xim, q % 49, q / 49, sm);
  }
}

// ---------------------------------------------------------------------------
// k_mega2: 1280 blocks scrambled (*521 mod 1280):
// id<512 conv | <1024 attn | else spatial
// ---------------------------------------------------------------------------
__global__ __launch_bounds__(256) void k_mega2(
    const u8* __restrict__ weff, const u16* __restrict__ xim, float* __restrict__ partial,
    const float* __restrict__ ra_qkv, const float* __restrict__ aa_qkv,
    const float* __restrict__ relpos, float* __restrict__ r0, float* __restrict__ ao,
    const float* __restrict__ normed, const float* __restrict__ h1_g,
    const float* __restrict__ sa_w2, const float* __restrict__ sa_b2,
    const float* __restrict__ sa_g, const float* __restrict__ sa_bb,
    float* __restrict__ spat_g)
{
  __shared__ float sm[12103];
  int id = (int)(((long long)blockIdx.x * 521) % 1280);
  if (id < 512){
    dev_conv(weff, xim, partial, id % 16, id / 16);
  } else if (id < 1024){
    int q = id - 512;
    dev_attn(ra_qkv, aa_qkv, relpos, r0, ao, q % 16, q / 16, sm);
  } else {
    int q = id - 1024;
    dev_spatial(normed, h1_g, sa_w2, sa_b2, sa_g, sa_bb, spat_g, q % 8, q / 8, sm);
  }
}

// ---------------------------------------------------------------------------
// k_proj3: bx<8 ra_proj, <16 aa_out (K=512), else ad_proj (act = 8-way
// partial sum, inline reduce)
// ---------------------------------------------------------------------------
__global__ __launch_bounds__(256) void k_proj3(
    const float* __restrict__ ra_pw, const float* __restrict__ ra_pb, const float* __restrict__ r0,
    const float* __restrict__ aa_ow, const float* __restrict__ aa_ob, const float* __restrict__ aa_o,
    const float* __restrict__ ad_pw, const float* __restrict__ ad_pb, const float* __restrict__ partial,
    const float* __restrict__ normed,
    float* __restrict__ rotf, float* __restrict__ angf, float* __restrict__ adpf)
{
  int bx = blockIdx.x, b = blockIdx.y;
  if (bx < 8){
    int m0 = (bx >> 2) * 128, p0 = (bx & 3) * 16;
    mfma_gemm_dev(ra_pw, ra_pb, r0, normed, rotf, 256, 256, m0, p0, b,
                  nullptr, nullptr, nullptr, nullptr);
  } else if (bx < 16){
    int bx2 = bx - 8;
    int m0 = (bx2 >> 2) * 128, p0 = (bx2 & 3) * 16;
    mfma_gemm_dev(aa_ow, aa_ob, aa_o, normed, angf, 256, 512, m0, p0, b,
                  nullptr, nullptr, nullptr, nullptr);
  } else {
    int bx2 = bx - 16;
    int m0 = (bx2 >> 2) * 128, p0 = (bx2 & 3) * 16;
    mfma_gemm_dev(ad_pw, ad_pb, partial /*unused as act*/, normed, adpf, 256, 256, m0, p0, b,
                  nullptr, nullptr, nullptr, nullptr, partial);
  }
}

// k_final: out = proj_w @ fused + proj_b + x, fused computed on the fly
__global__ __launch_bounds__(256) void k_final(
    const float* __restrict__ proj_w, const float* __restrict__ proj_b,
    const float* __restrict__ spat, const float* __restrict__ rotf,
    const float* __restrict__ angf, const float* __restrict__ adpf,
    const float* __restrict__ gates, const float* __restrict__ x,
    float* __restrict__ out)
{
  int bx = blockIdx.x, b = blockIdx.y;
  int wv = threadIdx.x >> 6, lane = threadIdx.x & 63;
  int lo = lane & 15, hi = lane >> 4;
  int m0 = (bx >> 2) * 128 + wv * 32;
  int p0 = (bx & 3) * 16;
  int p = p0 + lo;
  bool pok = p < 49;
  float g0 = 0.f, g1 = 0.f, g2 = 0.f, g3 = 0.f;
  if (pok){
    const float* g = gates + (size_t)b * 196 + p;
    g0 = g[0]; g1 = g[49]; g2 = g[98]; g3 = g[147];
  }
  size_t boff = (size_t)b * 12544;
  f32x4 acc0 = {0.f, 0.f, 0.f, 0.f};
  f32x4 acc1 = {0.f, 0.f, 0.f, 0.f};
  const float* wr0 = proj_w + (size_t)(m0 + lo) * 256 + hi * 8;
  const float* wr1 = wr0 + 16 * 256;
  for (int k0 = 0; k0 < 256; k0 += 32){
    int kb = k0 + hi * 8;
    float4 a0lo = *(const float4*)(wr0 + k0);
    float4 a0hi = *(const float4*)(wr0 + k0 + 4);
    float4 a1lo = *(const float4*)(wr1 + k0);
    float4 a1hi = *(const float4*)(wr1 + k0 + 4);
    float bv[8];
    if (pok){
      size_t base = boff + (size_t)kb * 49 + p;
      #pragma unroll
      for (int i = 0; i < 8; i++){
        size_t idx = base + (size_t)i * 49;
        bv[i] = spat[idx] * g0 + rotf[idx] * g1 + angf[idx] * g2 + adpf[idx] * g3;
      }
    } else {
      #pragma unroll
      for (int i = 0; i < 8; i++) bv[i] = 0.f;
    }
    BF8 A0, A1, B;
    A0.u[0] = pk2(a0lo.x, a0lo.y); A0.u[1] = pk2(a0lo.z, a0lo.w);
    A0.u[2] = pk2(a0hi.x, a0hi.y); A0.u[3] = pk2(a0hi.z, a0hi.w);
    A1.u[0] = pk2(a1lo.x, a1lo.y); A1.u[1] = pk2(a1lo.z, a1lo.w);
    A1.u[2] = pk2(a1hi.x, a1hi.y); A1.u[3] = pk2(a1hi.z, a1hi.w);
    B.u[0] = pk2(bv[0], bv[1]); B.u[1] = pk2(bv[2], bv[3]);
    B.u[2] = pk2(bv[4], bv[5]); B.u[3] = pk2(bv[6], bv[7]);
    acc0 = __builtin_amdgcn_mfma_f32_16x16x32_bf16(A0.v, B.v, acc0, 0, 0, 0);
    acc1 = __builtin_amdgcn_mfma_f32_16x16x32_bf16(A1.v, B.v, acc1, 0, 0, 0);
  }
  if (pok){
    #pragma unroll
    for (int r = 0; r < 4; r++){
      int m = m0 + hi * 4 + r;
      size_t idx = boff + (size_t)m * 49 + p;
      out[idx] = acc0[r] + proj_b[m] + x[idx];
      int m2 = m + 16;
      size_t idx2 = idx + 16 * 49;
      out[idx2] = acc1[r] + proj_b[m2] + x[idx2];
    }
  }
}

// ---------------------------------------------------------------------------
extern "C" void kernel_launch(void* const* d_in, const int* in_sizes, int n_in,
                              void* d_out, int out_size, void* d_ws, size_t ws_size,
                              hipStream_t stream)
{
  const float* x        = (const float*)d_in[0];
  const float* gn_g     = (const float*)d_in[1];
  const float* gn_b     = (const float*)d_in[2];
  const float* sa_w1    = (const float*)d_in[3];
  const float* sa_b1    = (const float*)d_in[4];
  const float* sa_w2    = (const float*)d_in[5];
  const float* sa_b2    = (const float*)d_in[6];
  const float* sa_gn_g  = (const float*)d_in[7];
  const float* sa_gn_b  = (const float*)d_in[8];
  const float* ra_gn_g  = (const float*)d_in[9];
  const float* ra_gn_b  = (const float*)d_in[10];
  const float* ra_qkv_w = (const float*)d_in[11];
  const float* ra_proj_w= (const float*)d_in[12];
  const float* ra_proj_b= (const float*)d_in[13];
  const float* aa_ln_g  = (const float*)d_in[14];
  const float* aa_ln_b  = (const float*)d_in[15];
  const float* aa_qkv_w = (const float*)d_in[16];
  const float* aa_relpos= (const float*)d_in[17];
  const float* aa_out_w = (const float*)d_in[18];
  const float* aa_out_b = (const float*)d_in[19];
  const float* ad_dir_w = (const float*)d_in[20];
  const float* ad_ap_w1 = (const float*)d_in[21];
  const float* ad_ap_b1 = (const float*)d_in[22];
  const float* ad_ap_w2 = (const float*)d_in[23];
  const float* ad_ap_b2 = (const float*)d_in[24];
  const float* ad_proj_w= (const float*)d_in[25];
  const float* ad_proj_b= (const float*)d_in[26];
  const float* gate_w   = (const float*)d_in[27];
  const float* gate_b   = (const float*)d_in[28];
  const float* proj_w   = (const float*)d_in[29];
  const float* proj_b   = (const float*)d_in[30];

  char* ws = (char*)d_ws;
  float* normed    = (float*)(ws + 0);
  float* xr        = (float*)(ws + 1605632);
  float* h1_g      = (float*)(ws + 3211264);
  float* lnm       = (float*)(ws + 3420160);
  float* lnr       = (float*)(ws + 3426560);
  float* spatial   = (float*)(ws + 4816896);
  float* rotf      = (float*)(ws + 6422528);
  float* anglef    = (float*)(ws + 8028160);
  float* adaptf    = (float*)(ws + 9633792);
  float* r0        = (float*)(ws + 12845056);
  float* gap       = (float*)(ws + 14450688);
  float* aw        = (float*)(ws + 14483456);
  float* gates     = (float*)(ws + 14485504);
  float* ra_qkv    = (float*)(ws + 14510592);
  float* aa_qkv    = (float*)(ws + 19327488);
  float* aa_o      = (float*)(ws + 28961280);
  float* partial   = (float*)(ws + 33778176);   // 12,845,056 B
  u16*   xim       = (u16*)  (ws + 46623232);   // 20,070,400 B
  u8*    weff      = (u8*)   (ws + 66693632);   // 52,428,800 B (fp8)

  float* out = (float*)d_out;

  k_prep1<<<dim3(8, 32), 256, 0, stream>>>(x, gn_g, gn_b, ra_gn_g, ra_gn_b, normed, xr, gap);
  k_pre2<<<dim3(15, 32), 256, 0, stream>>>(x, normed, gate_w, gate_b,
                                           sa_w1, sa_b1, ad_ap_w1, ad_ap_b1, ad_ap_w2, ad_ap_b2,
                                           gap, gates, lnm, lnr, h1_g, aw);
  k_mega1<<<dim3(5472), 256, 0, stream>>>(ad_dir_w, aw, weff,
                                          ra_qkv_w, aa_qkv_w, xr, normed,
                                          lnm, lnr, aa_ln_g, aa_ln_b, ra_qkv, aa_qkv,
                                          xim);
  k_mega2<<<dim3(1280), 256, 0, stream>>>(weff, xim, partial,
                                          ra_qkv, aa_qkv, aa_relpos, r0, aa_o,
                                          normed, h1_g, sa_w2, sa_b2, sa_gn_g, sa_gn_b, spatial);
  k_proj3<<<dim3(24, 32), 256, 0, stream>>>(ra_proj_w, ra_proj_b, r0,
                                            aa_out_w, aa_out_b, aa_o,
                                            ad_proj_w, ad_proj_b, partial,
                                            normed, rotf, anglef, adaptf);
  k_final<<<dim3(8, 32), 256, 0, stream>>>(proj_w, proj_b, spatial, rotf, anglef, adaptf,
                                           gates, x, out);
}

// Round 18
// 248.264 us; speedup vs baseline: 1.0829x; 1.0829x over previous
//
#include <hip/hip_runtime.h>

#define EPS 1e-5f
typedef unsigned char u8;
typedef unsigned short u16;
typedef unsigned int u32;
typedef float f32x2 __attribute__((ext_vector_type(2)));
typedef float f32x4 __attribute__((ext_vector_type(4)));
typedef short bf16x8 __attribute__((ext_vector_type(8)));
typedef unsigned int u32x2 __attribute__((ext_vector_type(2)));

__device__ __forceinline__ float bf2f(u16 h){
  return __uint_as_float(((u32)h) << 16);
}
// software RNE f32->bf16 (scalar u16 stores only)
__device__ __forceinline__ u16 f2bf(float f){
  u32 u = __float_as_uint(f);
  u += 0x7fffu + ((u >> 16) & 1u);
  return (u16)(u >> 16);
}
// HW packed f32x2 -> bf16x2 (lo in [15:0], hi in [31:16])
__device__ __forceinline__ u32 pk2(float lo, float hi){
  u32 r;
  asm("v_cvt_pk_bf16_f32 %0, %1, %2" : "=v"(r) : "v"(lo), "v"(hi));
  return r;
}
union BF8 { bf16x8 v; u32 u[4]; };

// fp8x8 (packed in u32x2) -> bf16x8 via HW cvt (8 VALU ops total)
__device__ __forceinline__ bf16x8 fp8_to_bf16x8(u32x2 a){
  f32x2 f01 = __builtin_amdgcn_cvt_pk_f32_fp8(a.x, false);
  f32x2 f23 = __builtin_amdgcn_cvt_pk_f32_fp8(a.x, true);
  f32x2 f45 = __builtin_amdgcn_cvt_pk_f32_fp8(a.y, false);
  f32x2 f67 = __builtin_amdgcn_cvt_pk_f32_fp8(a.y, true);
  BF8 r;
  r.u[0] = pk2(f01.x, f01.y); r.u[1] = pk2(f23.x, f23.y);
  r.u[2] = pk2(f45.x, f45.y); r.u[3] = pk2(f67.x, f67.y);
  return r.v;
}

// ---------------------------------------------------------------------------
// k_prep1: GN(x)->normed, GN(normed)->xr, gap. grid(8,32).
// ---------------------------------------------------------------------------
__global__ __launch_bounds__(256) void k_prep1(
    const float* __restrict__ x, const float* __restrict__ gn_g, const float* __restrict__ gn_b,
    const float* __restrict__ ra_g, const float* __restrict__ ra_b,
    float* __restrict__ normed, float* __restrict__ xr, float* __restrict__ gap)
{
  int ch = blockIdx.x, b = blockIdx.y;
  int c0 = ch * 32;
  __shared__ float xs[1568], ns[1568];
  const float* xb = x + ((size_t)b * 256 + c0) * 49;
  for (int i = threadIdx.x; i < 1568; i += 256) xs[i] = xb[i];
  __syncthreads();
  int wv = threadIdx.x >> 6, lane = threadIdx.x & 63;
  const float* gsrc = xs + wv * 392;
  float* ndst = ns + wv * 392;
  float s = 0.f, ss = 0.f;
  for (int i = lane; i < 392; i += 64){ float v = gsrc[i]; s += v; ss += v * v; }
  for (int off = 32; off; off >>= 1){ s += __shfl_down(s, off); ss += __shfl_down(ss, off); }
  s = __shfl(s, 0); ss = __shfl(ss, 0);
  float m = s / 392.f, rs = rsqrtf(ss / 392.f - m * m + EPS);
  for (int i = lane; i < 392; i += 64){
    int c = c0 + wv * 8 + i / 49;
    ndst[i] = (gsrc[i] - m) * rs * gn_g[c] + gn_b[c];
  }
  __syncthreads();
  float* nb = normed + ((size_t)b * 256 + c0) * 49;
  for (int i = threadIdx.x; i < 1568; i += 256) nb[i] = ns[i];
  if (threadIdx.x < 32){
    float g2 = 0.f; const float* rp = ns + threadIdx.x * 49;
    for (int p = 0; p < 49; p++) g2 += rp[p];
    gap[(size_t)b * 256 + c0 + threadIdx.x] = g2 * (1.f / 49.f);
  }
  s = 0.f; ss = 0.f;
  for (int i = lane; i < 392; i += 64){ float v = ndst[i]; s += v; ss += v * v; }
  for (int off = 32; off; off >>= 1){ s += __shfl_down(s, off); ss += __shfl_down(ss, off); }
  s = __shfl(s, 0); ss = __shfl(ss, 0);
  m = s / 392.f; rs = rsqrtf(ss / 392.f - m * m + EPS);
  float* xrb = xr + ((size_t)b * 256 + c0) * 49;
  for (int i = lane; i < 392; i += 64){
    int c = c0 + wv * 8 + i / 49;
    xrb[wv * 392 + i] = (ndst[i] - m) * rs * ra_g[c] + ra_b[c];
  }
}

// ---------------------------------------------------------------------------
// dev_pos / dev_h1aw  (merged into k_pre2)
// ---------------------------------------------------------------------------
__device__ void dev_pos(
    const float* __restrict__ x, const float* __restrict__ normed,
    const float* __restrict__ gate_w, const float* __restrict__ gate_b,
    float* __restrict__ gates_g, float* __restrict__ lnm_g, float* __restrict__ lnr_g,
    int pc, int b, float* sm)
{
  float* gw = sm;  // 1024
  for (int i = threadIdx.x; i < 1024; i += 256) gw[i] = gate_w[i];
  __syncthreads();
  int wv = threadIdx.x >> 6, lane = threadIdx.x & 63;
  for (int pi = wv; pi < 7; pi += 4){
    int p = pc * 7 + pi;
    const float* nb = normed + (size_t)b * 12544 + p;
    const float* xb = x + (size_t)b * 12544 + p;
    float s = 0.f, ss = 0.f, g0 = 0.f, g1 = 0.f, g2 = 0.f, g3 = 0.f;
    for (int c = lane; c < 256; c += 64){
      float nv = nb[c * 49];
      float xv = xb[c * 49];
      s += nv; ss += nv * nv;
      g0 += xv * gw[c]; g1 += xv * gw[256 + c];
      g2 += xv * gw[512 + c]; g3 += xv * gw[768 + c];
    }
    for (int off = 32; off; off >>= 1){
      s += __shfl_down(s, off); ss += __shfl_down(ss, off);
      g0 += __shfl_down(g0, off); g1 += __shfl_down(g1, off);
      g2 += __shfl_down(g2, off); g3 += __shfl_down(g3, off);
    }
    if (lane == 0){
      float mu = s / 256.f;
      lnm_g[b * 49 + p] = mu;
      lnr_g[b * 49 + p] = rsqrtf(ss / 256.f - mu * mu + EPS);
      g0 += gate_b[0]; g1 += gate_b[1]; g2 += gate_b[2]; g3 += gate_b[3];
      float mx = fmaxf(fmaxf(g0, g1), fmaxf(g2, g3));
      float e0 = __expf(g0 - mx), e1 = __expf(g1 - mx), e2 = __expf(g2 - mx), e3 = __expf(g3 - mx);
      float inv = 1.f / (e0 + e1 + e2 + e3);
      float* gg = gates_g + (size_t)b * 196 + p;
      gg[0] = e0 * inv; gg[49] = e1 * inv; gg[98] = e2 * inv; gg[147] = e3 * inv;
    }
  }
}

__device__ void dev_h1aw(
    const float* __restrict__ normed, const float* __restrict__ sa_w1, const float* __restrict__ sa_b1,
    const float* __restrict__ ap_w1, const float* __restrict__ ap_b1,
    const float* __restrict__ ap_w2, const float* __restrict__ ap_b2,
    const float* __restrict__ gap_g,
    float* __restrict__ h1_g, float* __restrict__ aw_g,
    int xb2, int b, float* sm)
{
  int t = threadIdx.x;
  if (xb2 == 7){
    float* gaps = sm; float* h = sm + 256; float* lg = sm + 384;
    gaps[t] = gap_g[b * 256 + t];
    __syncthreads();
    if (t < 128){
      float s = ap_b1[t];
      const float* wr = ap_w1 + t * 256;
      #pragma unroll 4
      for (int c = 0; c < 256; c++) s += gaps[c] * wr[c];
      h[t] = fmaxf(s, 0.f);
    }
    __syncthreads();
    if (t < 16){
      float s = ap_b2[t];
      const float* wr = ap_w2 + t * 128;
      #pragma unroll 4
      for (int o = 0; o < 128; o++) s += h[o] * wr[o];
      lg[t] = s;
    }
    __syncthreads();
    if (t == 0){
      float mx = -1e30f;
      for (int k = 0; k < 16; k++) mx = fmaxf(mx, lg[k]);
      float e[16], smm = 0.f;
      for (int k = 0; k < 16; k++){ e[k] = __expf(lg[k] - mx); smm += e[k]; }
      float inv = 1.f / smm;
      for (int k = 0; k < 16; k++) aw_g[b * 16 + k] = e[k] * inv;
    }
    return;
  }
  float* w1t = sm;            // 8448
  float* ns2 = sm + 8448;     // 1792
  int p0 = xb2 * 7;
  for (int i = t; i < 8192; i += 256){
    int o = i >> 8, c = i & 255;
    w1t[c * 33 + o] = sa_w1[i];
  }
  for (int i = t; i < 1792; i += 256){
    int c = i / 7, pl = i - c * 7;
    ns2[i] = normed[(size_t)b * 12544 + c * 49 + p0 + pl];
  }
  __syncthreads();
  if (t < 224){
    int pl = t >> 5, o = t & 31;
    float s = sa_b1[o];
    #pragma unroll 8
    for (int c = 0; c < 256; c++) s += ns2[c * 7 + pl] * w1t[c * 33 + o];
    h1_g[(size_t)b * 1568 + (p0 + pl) * 32 + o] = fmaxf(s, 0.f);
  }
}

__global__ __launch_bounds__(256) void k_pre2(
    const float* __restrict__ x, const float* __restrict__ normed,
    const float* __restrict__ gate_w, const float* __restrict__ gate_b,
    const float* __restrict__ sa_w1, const float* __restrict__ sa_b1,
    const float* __restrict__ ap_w1, const float* __restrict__ ap_b1,
    const float* __restrict__ ap_w2, const float* __restrict__ ap_b2,
    const float* __restrict__ gap_g,
    float* __restrict__ gates_g, float* __restrict__ lnm_g, float* __restrict__ lnr_g,
    float* __restrict__ h1_g, float* __restrict__ aw_g)
{
  __shared__ float sm[10240];
  int bx = blockIdx.x, b = blockIdx.y;
  if (bx < 7)
    dev_pos(x, normed, gate_w, gate_b, gates_g, lnm_g, lnr_g, bx, b, sm);
  else
    dev_h1aw(normed, sa_w1, sa_b1, ap_w1, ap_b1, ap_w2, ap_b2, gap_g, h1_g, aw_g, bx - 7, b, sm);
}

// ---------------------------------------------------------------------------
// device pieces
// ---------------------------------------------------------------------------
__device__ void dev_spatial(
    const float* __restrict__ normed, const float* __restrict__ h1_g,
    const float* __restrict__ sa_w2, const float* __restrict__ sa_b2,
    const float* __restrict__ sa_g, const float* __restrict__ sa_bb,
    float* __restrict__ spat_g, int gc, int b, float* sm)
{
  float* h1s = sm;           // 1617
  float* w2s = sm + 1617;    // 1024
  int t = threadIdx.x;
  for (int i = t; i < 1568; i += 256){
    int p = i >> 5, o = i & 31;
    h1s[p * 33 + o] = h1_g[(size_t)b * 1568 + i];
  }
  for (int i = t; i < 1024; i += 256) w2s[i] = sa_w2[gc * 1024 + i];
  __syncthreads();
  int wv = t >> 6, lane = t & 63;
  int cg0 = wv * 8;
  const float* nb = normed + (size_t)b * 12544 + (gc * 32 + cg0) * 49;
  float tmp[7];
  float s = 0.f, ss = 0.f;
  #pragma unroll
  for (int j = 0; j < 7; j++){
    int i = lane + 64 * j;
    float v = 0.f;
    if (i < 392){
      int c = i / 49;
      const float* wr = w2s + (cg0 + c) * 32;
      const float* hp = h1s + (i - c * 49) * 33;
      float d = sa_b2[gc * 32 + cg0 + c];
      #pragma unroll
      for (int o = 0; o < 32; o++) d += hp[o] * wr[o];
      v = nb[i] * (1.f + 1.f / (1.f + __expf(-d)));
      s += v; ss += v * v;
    }
    tmp[j] = v;
  }
  for (int off = 32; off; off >>= 1){ s += __shfl_down(s, off); ss += __shfl_down(ss, off); }
  s = __shfl(s, 0); ss = __shfl(ss, 0);
  float m = s / 392.f, rs = rsqrtf(ss / 392.f - m * m + EPS);
  float* sb = spat_g + (size_t)b * 12544 + (gc * 32 + cg0) * 49;
  #pragma unroll
  for (int j = 0; j < 7; j++){
    int i = lane + 64 * j;
    if (i < 392){
      int c = gc * 32 + cg0 + i / 49;
      sb[i] = (tmp[j] - m) * rs * sa_g[c] + sa_bb[c];
    }
  }
}

// weff: fp8 e4m3, pre-scaled x16 (decode side folds 1/16 into xim).
__device__ void dev_weff(
    const float* __restrict__ W, const float* __restrict__ aw, u8* __restrict__ weff, int bx)
{
  const size_t t = ((size_t)bx * 256 + threadIdx.x) * 4;
  float4 A[16];
  #pragma unroll
  for (int k = 0; k < 16; k++) A[k] = *(const float4*)(W + (size_t)k * 1638400 + t);
  #pragma unroll 1
  for (int b = 0; b < 32; b++){
    float s0 = 0.f, s1 = 0.f, s2 = 0.f, s3 = 0.f;
    #pragma unroll
    for (int k = 0; k < 16; k++){
      float a = aw[b * 16 + k];
      s0 += a * A[k].x; s1 += a * A[k].y; s2 += a * A[k].z; s3 += a * A[k].w;
    }
    int pk = __builtin_amdgcn_cvt_pk_fp8_f32(s0 * 16.f, s1 * 16.f, 0, false);
    pk = __builtin_amdgcn_cvt_pk_fp8_f32(s2 * 16.f, s3 * 16.f, pk, true);
    __builtin_nontemporal_store((u32)pk, (u32*)(weff + (size_t)b * 1638400 + t));
  }
}

// im2col: xim = bf16(normed/16); zero outside image.
__device__ void dev_im2col(
    const float* __restrict__ normed, u16* __restrict__ xim, int p, int b, float* sm)
{
  u16* row = (u16*)sm;  // 6400 u16
  int ci = threadIdx.x;
  int py = p / 7, px = p - py * 7;
  const float* nb = normed + (size_t)b * 12544 + ci * 49;
  u16* rp = row + ci * 25;
  #pragma unroll
  for (int sy = 0; sy < 5; sy++){
    int iy = py + sy - 2;
    #pragma unroll
    for (int sx = 0; sx < 5; sx++){
      int ix = px + sx - 2;
      float v = (iy >= 0 && iy < 7 && ix >= 0 && ix < 7) ? nb[iy * 7 + ix] * 0.0625f : 0.f;
      rp[sy * 5 + sx] = f2bf(v);
    }
  }
  __syncthreads();
  const u32* rs = (const u32*)row;
  u32* od = (u32*)(xim + (size_t)(b * 49 + p) * 6400);
  for (int i = threadIdx.x; i < 3200; i += 256) od[i] = rs[i];
}

// mfma_gemm_dev: per-wave 32m x 16p tile; optional LN-fused act, optional
// 8-way partial-sum act (part8 != nullptr reads Sum_kp partial instead).
__device__ __forceinline__ void mfma_gemm_dev(
    const float* __restrict__ W, const float* __restrict__ bias,
    const float* __restrict__ act, const float* __restrict__ res,
    float* __restrict__ out, int M, int K, int m0blk, int p0, int b,
    const float* __restrict__ lnm, const float* __restrict__ lnr,
    const float* __restrict__ lng, const float* __restrict__ lnb,
    const float* __restrict__ part8 = nullptr)
{
  int wv = threadIdx.x >> 6, lane = threadIdx.x & 63;
  int lo = lane & 15, hi = lane >> 4;
  int m0 = m0blk + wv * 32;
  int p = p0 + lo;
  bool pok = p < 49;
  const float* ab = act + (size_t)b * K * 49;
  float lm = 0.f, lr = 0.f;
  if (lng && pok){ lm = lnm[p]; lr = lnr[p]; }
  f32x4 acc0 = {0.f, 0.f, 0.f, 0.f};
  f32x4 acc1 = {0.f, 0.f, 0.f, 0.f};
  const float* wr0 = W + (size_t)(m0 + lo) * K + hi * 8;
  const float* wr1 = W + (size_t)(m0 + 16 + lo) * K + hi * 8;
  for (int k0 = 0; k0 < K; k0 += 32){
    int kb = k0 + hi * 8;
    float4 a0lo = *(const float4*)(wr0 + k0);
    float4 a0hi = *(const float4*)(wr0 + k0 + 4);
    float4 a1lo = *(const float4*)(wr1 + k0);
    float4 a1hi = *(const float4*)(wr1 + k0 + 4);
    float bv[8];
    if (pok){
      if (part8){
        const float* pp = part8 + (size_t)b * 12544 + (size_t)kb * 49 + p;
        #pragma unroll
        for (int i = 0; i < 8; i++){
          float s = 0.f;
          #pragma unroll
          for (int kp = 0; kp < 8; kp++) s += pp[(size_t)kp * 401408 + i * 49];
          bv[i] = s;
        }
      } else {
        const float* ap = ab + (size_t)kb * 49 + p;
        #pragma unroll
        for (int i = 0; i < 8; i++) bv[i] = ap[i * 49];
        if (lng){
          #pragma unroll
          for (int i = 0; i < 8; i++) bv[i] = (bv[i] - lm) * lr * lng[kb + i] + lnb[kb + i];
        }
      }
    } else {
      #pragma unroll
      for (int i = 0; i < 8; i++) bv[i] = 0.f;
    }
    BF8 A0, A1, B;
    A0.u[0] = pk2(a0lo.x, a0lo.y); A0.u[1] = pk2(a0lo.z, a0lo.w);
    A0.u[2] = pk2(a0hi.x, a0hi.y); A0.u[3] = pk2(a0hi.z, a0hi.w);
    A1.u[0] = pk2(a1lo.x, a1lo.y); A1.u[1] = pk2(a1lo.z, a1lo.w);
    A1.u[2] = pk2(a1hi.x, a1hi.y); A1.u[3] = pk2(a1hi.z, a1hi.w);
    B.u[0] = pk2(bv[0], bv[1]); B.u[1] = pk2(bv[2], bv[3]);
    B.u[2] = pk2(bv[4], bv[5]); B.u[3] = pk2(bv[6], bv[7]);
    acc0 = __builtin_amdgcn_mfma_f32_16x16x32_bf16(A0.v, B.v, acc0, 0, 0, 0);
    acc1 = __builtin_amdgcn_mfma_f32_16x16x32_bf16(A1.v, B.v, acc1, 0, 0, 0);
  }
  if (pok){
    #pragma unroll
    for (int r = 0; r < 4; r++){
      int m = m0 + hi * 4 + r;
      size_t idx = ((size_t)b * M + m) * 49 + p;
      float v = acc0[r] + (bias ? bias[m] : 0.f);
      if (res) v += res[idx];
      out[idx] = v;
      int m2 = m + 16;
      size_t idx2 = idx + 16 * 49;
      float v2 = acc1[r] + (bias ? bias[m2] : 0.f);
      if (res) v2 += res[idx2];
      out[idx2] = v2;
    }
  }
}

__device__ void dev_conv(
    const u8* __restrict__ weff, const u16* __restrict__ xim, float* __restrict__ partial,
    int bx, int b)
{
  int mblk = bx >> 3, kp = bx & 7;
  int wv = threadIdx.x >> 6, lane = threadIdx.x & 63;
  int lo = lane & 15, hi = lane >> 4;
  int co0 = mblk * 128 + wv * 32;
  const u8* wr0 = weff + (size_t)b * 1638400 + (size_t)(co0 + lo) * 6400 + kp * 800 + hi * 8;
  const u8* wr1 = wr0 + 16 * 6400;
  const u16* xb = xim + (size_t)b * 313600 + (size_t)lo * 6400 + kp * 800 + hi * 8;
  f32x4 acc[2][4];
  #pragma unroll
  for (int mi = 0; mi < 2; mi++)
    #pragma unroll
    for (int pi = 0; pi < 4; pi++) acc[mi][pi] = (f32x4){0.f, 0.f, 0.f, 0.f};
  #pragma unroll 1
  for (int ks = 0; ks < 25; ks++){
    int k0 = ks * 32;
    u32x2 a0p = __builtin_nontemporal_load((const u32x2*)(wr0 + k0));
    u32x2 a1p = __builtin_nontemporal_load((const u32x2*)(wr1 + k0));
    bf16x8 A0 = fp8_to_bf16x8(a0p);
    bf16x8 A1 = fp8_to_bf16x8(a1p);
    bf16x8 B0 = *(const bf16x8*)(xb + k0);
    bf16x8 B1 = *(const bf16x8*)(xb + 16 * 6400 + k0);
    bf16x8 B2 = *(const bf16x8*)(xb + 32 * 6400 + k0);
    bf16x8 B3 = *(const bf16x8*)(xb + 48 * 6400 + k0);
    acc[0][0] = __builtin_amdgcn_mfma_f32_16x16x32_bf16(A0, B0, acc[0][0], 0, 0, 0);
    acc[0][1] = __builtin_amdgcn_mfma_f32_16x16x32_bf16(A0, B1, acc[0][1], 0, 0, 0);
    acc[0][2] = __builtin_amdgcn_mfma_f32_16x16x32_bf16(A0, B2, acc[0][2], 0, 0, 0);
    acc[0][3] = __builtin_amdgcn_mfma_f32_16x16x32_bf16(A0, B3, acc[0][3], 0, 0, 0);
    acc[1][0] = __builtin_amdgcn_mfma_f32_16x16x32_bf16(A1, B0, acc[1][0], 0, 0, 0);
    acc[1][1] = __builtin_amdgcn_mfma_f32_16x16x32_bf16(A1, B1, acc[1][1], 0, 0, 0);
    acc[1][2] = __builtin_amdgcn_mfma_f32_16x16x32_bf16(A1, B2, acc[1][2], 0, 0, 0);
    acc[1][3] = __builtin_amdgcn_mfma_f32_16x16x32_bf16(A1, B3, acc[1][3], 0, 0, 0);
  }
  float* pb = partial + ((size_t)kp * 32 + b) * 12544;
  #pragma unroll
  for (int mi = 0; mi < 2; mi++){
    #pragma unroll
    for (int pi = 0; pi < 4; pi++){
      int p = pi * 16 + lo;
      if (p < 49){
        #pragma unroll
        for (int r = 0; r < 4; r++){
          int co = co0 + mi * 16 + hi * 4 + r;
          pb[co * 49 + p] = acc[mi][pi][r];
        }
      }
    }
  }
}

__device__ __forceinline__ void softmax_rows(float* sc, int tid)
{
  int r = tid >> 2, q = tid & 3;
  if (r < 49){
    float* row = sc + r * 52;
    float mx = -1e30f;
    for (int j = q; j < 49; j += 4) mx = fmaxf(mx, row[j]);
    mx = fmaxf(mx, __shfl_xor(mx, 1));
    mx = fmaxf(mx, __shfl_xor(mx, 2));
    float sm = 0.f;
    for (int j = q; j < 49; j += 4){ float e = __expf(row[j] - mx); row[j] = e; sm += e; }
    sm += __shfl_xor(sm, 1);
    sm += __shfl_xor(sm, 2);
    float inv = 1.f / sm;
    for (int j = q; j < 49; j += 4) row[j] *= inv;
  }
}

__device__ void dev_attn(
    const float* __restrict__ ra_qkv, const float* __restrict__ aa_qkv,
    const float* __restrict__ relpos,
    float* __restrict__ r0, float* __restrict__ ao,
    int xb2, int b, float* sm)
{
  if (xb2 < 8){
    int hd = xb2;
    float* qs = sm; float* ks = sm + 1617; float* vs = sm + 3234; float* sc = sm + 4851;
    const float* base = ra_qkv + (size_t)b * 768 * 49;
    for (int i = threadIdx.x; i < 1568; i += 256){
      int d = i / 49, tok = i - d * 49;
      qs[tok * 33 + d] = base[(hd * 32 + d) * 49 + tok];
      ks[tok * 33 + d] = base[(256 + hd * 32 + d) * 49 + tok];
      vs[tok * 33 + d] = base[(512 + hd * 32 + d) * 49 + tok];
    }
    __syncthreads();
    const float scale = 0.17677669529663687f;
    for (int it = threadIdx.x; it < 2401; it += 256){
      int i = it / 49, j = it - i * 49;
      float s = 0.f;
      #pragma unroll
      for (int d = 0; d < 32; d++) s += qs[i * 33 + d] * ks[j * 33 + d];
      sc[i * 52 + j] = s * scale;
    }
    __syncthreads();
    softmax_rows(sc, threadIdx.x);
    __syncthreads();
    for (int it = threadIdx.x; it < 1568; it += 256){
      int d = it / 49, i = it - d * 49;
      float o = 0.f;
      for (int j = 0; j < 49; j++) o += sc[i * 52 + j] * vs[j * 33 + d];
      r0[((size_t)b * 256 + hd * 32 + d) * 49 + i] = o;
    }
  } else {
    int hd = xb2 - 8;
    float* qs = sm; float* ks = sm + 3185; float* vs = sm + 6370; float* sc = sm + 9555;
    const float* base = aa_qkv + (size_t)b * 1536 * 49;
    for (int i = threadIdx.x; i < 3136; i += 256){
      int d = i / 49, tok = i - d * 49;
      qs[tok * 65 + d] = base[(hd * 64 + d) * 49 + tok];
      ks[tok * 65 + d] = base[(512 + hd * 64 + d) * 49 + tok];
      vs[tok * 65 + d] = base[(1024 + hd * 64 + d) * 49 + tok];
    }
    __syncthreads();
    for (int it = threadIdx.x; it < 2401; it += 256){
      int i = it / 49, j = it - i * 49;
      float s = 0.f;
      #pragma unroll
      for (int d = 0; d < 64; d++) s += qs[i * 65 + d] * ks[j * 65 + d];
      int dy = j / 7 - i / 7 + 6, dx = j % 7 - i % 7 + 6;
      sc[i * 52 + j] = s * 0.125f + relpos[(dy * 13 + dx) * 8 + hd];
    }
    __syncthreads();
    softmax_rows(sc, threadIdx.x);
    __syncthreads();
    for (int it = threadIdx.x; it < 3136; it += 256){
      int d = it / 49, i = it - d * 49;
      float o = 0.f;
      for (int j = 0; j < 49; j++) o += sc[i * 52 + j] * vs[j * 65 + d];
      ao[((size_t)b * 512 + hd * 64 + d) * 49 + i] = o;
    }
  }
}

// ---------------------------------------------------------------------------
// k_mega1: 5472 blocks scrambled (*2003 mod 5472):
// id<1600 weff | <3904 qkv | else im2col
// ---------------------------------------------------------------------------
__global__ __launch_bounds__(256) void k_mega1(
    const float* __restrict__ ad_dir_w, const float* __restrict__ aw, u8* __restrict__ weff,
    const float* __restrict__ ra_w, const float* __restrict__ aa_w,
    const float* __restrict__ xr, const float* __restrict__ normed,
    const float* __restrict__ lnm, const float* __restrict__ lnr,
    const float* __restrict__ ln_g, const float* __restrict__ ln_b,
    float* __restrict__ ra_qkv, float* __restrict__ aa_qkv,
    u16* __restrict__ xim)
{
  __shared__ float sm[3300];
  int id = (int)(((long long)blockIdx.x * 2003) % 5472);
  if (id < 1600){
    dev_weff(ad_dir_w, aw, weff, id);
  } else if (id < 3904){
    int q = id - 1600;
    int bx = q % 72, b = q / 72;
    if (bx < 24){
      int m0 = (bx >> 2) * 128, p0 = (bx & 3) * 16;
      mfma_gemm_dev(ra_w, nullptr, xr, nullptr, ra_qkv, 768, 256, m0, p0, b,
                    nullptr, nullptr, nullptr, nullptr);
    } else {
      int bx2 = bx - 24;
      int m0 = (bx2 >> 2) * 128, p0 = (bx2 & 3) * 16;
      mfma_gemm_dev(aa_w, nullptr, normed, nullptr, aa_qkv, 1536, 256, m0, p0, b,
                    lnm + b * 49, lnr + b * 49, ln_g, ln_b);
    }
  } else {
    int q = id - 3904;
    dev_im2col(normed, xim, q % 49, q / 49, sm);
  }
}

// ---------------------------------------------------------------------------
// k_mega2: 1280 blocks scrambled (*521 mod 1280):
// id<512 conv | <1024 attn | else spatial
// ---------------------------------------------------------------------------
__global__ __launch_bounds__(256) void k_mega2(
    const u8* __restrict__ weff, const u16* __restrict__ xim, float* __restrict__ partial,
    const float* __restrict__ ra_qkv, const float* __restrict__ aa_qkv,
    const float* __restrict__ relpos, float* __restrict__ r0, float* __restrict__ ao,
    const float* __restrict__ normed, const float* __restrict__ h1_g,
    const float* __restrict__ sa_w2, const float* __restrict__ sa_b2,
    const float* __restrict__ sa_g, const float* __restrict__ sa_bb,
    float* __restrict__ spat_g)
{
  __shared__ float sm[12103];
  int id = (int)(((long long)blockIdx.x * 521) % 1280);
  if (id < 512){
    dev_conv(weff, xim, partial, id % 16, id / 16);
  } else if (id < 1024){
    int q = id - 512;
    dev_attn(ra_qkv, aa_qkv, relpos, r0, ao, q % 16, q / 16, sm);
  } else {
    int q = id - 1024;
    dev_spatial(normed, h1_g, sa_w2, sa_b2, sa_g, sa_bb, spat_g, q % 8, q / 8, sm);
  }
}

// ---------------------------------------------------------------------------
// k_proj3: bx<8 ra_proj, <16 aa_out (K=512), else ad_proj (act = 8-way
// partial sum, inline reduce)
// ---------------------------------------------------------------------------
__global__ __launch_bounds__(256) void k_proj3(
    const float* __restrict__ ra_pw, const float* __restrict__ ra_pb, const float* __restrict__ r0,
    const float* __restrict__ aa_ow, const float* __restrict__ aa_ob, const float* __restrict__ aa_o,
    const float* __restrict__ ad_pw, const float* __restrict__ ad_pb, const float* __restrict__ partial,
    const float* __restrict__ normed,
    float* __restrict__ rotf, float* __restrict__ angf, float* __restrict__ adpf)
{
  int bx = blockIdx.x, b = blockIdx.y;
  if (bx < 8){
    int m0 = (bx >> 2) * 128, p0 = (bx & 3) * 16;
    mfma_gemm_dev(ra_pw, ra_pb, r0, normed, rotf, 256, 256, m0, p0, b,
                  nullptr, nullptr, nullptr, nullptr);
  } else if (bx < 16){
    int bx2 = bx - 8;
    int m0 = (bx2 >> 2) * 128, p0 = (bx2 & 3) * 16;
    mfma_gemm_dev(aa_ow, aa_ob, aa_o, normed, angf, 256, 512, m0, p0, b,
                  nullptr, nullptr, nullptr, nullptr);
  } else {
    int bx2 = bx - 16;
    int m0 = (bx2 >> 2) * 128, p0 = (bx2 & 3) * 16;
    mfma_gemm_dev(ad_pw, ad_pb, partial /*unused as act*/, normed, adpf, 256, 256, m0, p0, b,
                  nullptr, nullptr, nullptr, nullptr, partial);
  }
}

// k_final: out = proj_w @ fused + proj_b + x, fused computed on the fly
__global__ __launch_bounds__(256) void k_final(
    const float* __restrict__ proj_w, const float* __restrict__ proj_b,
    const float* __restrict__ spat, const float* __restrict__ rotf,
    const float* __restrict__ angf, const float* __restrict__ adpf,
    const float* __restrict__ gates, const float* __restrict__ x,
    float* __restrict__ out)
{
  int bx = blockIdx.x, b = blockIdx.y;
  int wv = threadIdx.x >> 6, lane = threadIdx.x & 63;
  int lo = lane & 15, hi = lane >> 4;
  int m0 = (bx >> 2) * 128 + wv * 32;
  int p0 = (bx & 3) * 16;
  int p = p0 + lo;
  bool pok = p < 49;
  float g0 = 0.f, g1 = 0.f, g2 = 0.f, g3 = 0.f;
  if (pok){
    const float* g = gates + (size_t)b * 196 + p;
    g0 = g[0]; g1 = g[49]; g2 = g[98]; g3 = g[147];
  }
  size_t boff = (size_t)b * 12544;
  f32x4 acc0 = {0.f, 0.f, 0.f, 0.f};
  f32x4 acc1 = {0.f, 0.f, 0.f, 0.f};
  const float* wr0 = proj_w + (size_t)(m0 + lo) * 256 + hi * 8;
  const float* wr1 = wr0 + 16 * 256;
  for (int k0 = 0; k0 < 256; k0 += 32){
    int kb = k0 + hi * 8;
    float4 a0lo = *(const float4*)(wr0 + k0);
    float4 a0hi = *(const float4*)(wr0 + k0 + 4);
    float4 a1lo = *(const float4*)(wr1 + k0);
    float4 a1hi = *(const float4*)(wr1 + k0 + 4);
    float bv[8];
    if (pok){
      size_t base = boff + (size_t)kb * 49 + p;
      #pragma unroll
      for (int i = 0; i < 8; i++){
        size_t idx = base + (size_t)i * 49;
        bv[i] = spat[idx] * g0 + rotf[idx] * g1 + angf[idx] * g2 + adpf[idx] * g3;
      }
    } else {
      #pragma unroll
      for (int i = 0; i < 8; i++) bv[i] = 0.f;
    }
    BF8 A0, A1, B;
    A0.u[0] = pk2(a0lo.x, a0lo.y); A0.u[1] = pk2(a0lo.z, a0lo.w);
    A0.u[2] = pk2(a0hi.x, a0hi.y); A0.u[3] = pk2(a0hi.z, a0hi.w);
    A1.u[0] = pk2(a1lo.x, a1lo.y); A1.u[1] = pk2(a1lo.z, a1lo.w);
    A1.u[2] = pk2(a1hi.x, a1hi.y); A1.u[3] = pk2(a1hi.z, a1hi.w);
    B.u[0] = pk2(bv[0], bv[1]); B.u[1] = pk2(bv[2], bv[3]);
    B.u[2] = pk2(bv[4], bv[5]); B.u[3] = pk2(bv[6], bv[7]);
    acc0 = __builtin_amdgcn_mfma_f32_16x16x32_bf16(A0.v, B.v, acc0, 0, 0, 0);
    acc1 = __builtin_amdgcn_mfma_f32_16x16x32_bf16(A1.v, B.v, acc1, 0, 0, 0);
  }
  if (pok){
    #pragma unroll
    for (int r = 0; r < 4; r++){
      int m = m0 + hi * 4 + r;
      size_t idx = boff + (size_t)m * 49 + p;
      out[idx] = acc0[r] + proj_b[m] + x[idx];
      int m2 = m + 16;
      size_t idx2 = idx + 16 * 49;
      out[idx2] = acc1[r] + proj_b[m2] + x[idx2];
    }
  }
}

// ---------------------------------------------------------------------------
extern "C" void kernel_launch(void* const* d_in, const int* in_sizes, int n_in,
                              void* d_out, int out_size, void* d_ws, size_t ws_size,
                              hipStream_t stream)
{
  const float* x        = (const float*)d_in[0];
  const float* gn_g     = (const float*)d_in[1];
  const float* gn_b     = (const float*)d_in[2];
  const float* sa_w1    = (const float*)d_in[3];
  const float* sa_b1    = (const float*)d_in[4];
  const float* sa_w2    = (const float*)d_in[5];
  const float* sa_b2    = (const float*)d_in[6];
  const float* sa_gn_g  = (const float*)d_in[7];
  const float* sa_gn_b  = (const float*)d_in[8];
  const float* ra_gn_g  = (const float*)d_in[9];
  const float* ra_gn_b  = (const float*)d_in[10];
  const float* ra_qkv_w = (const float*)d_in[11];
  const float* ra_proj_w= (const float*)d_in[12];
  const float* ra_proj_b= (const float*)d_in[13];
  const float* aa_ln_g  = (const float*)d_in[14];
  const float* aa_ln_b  = (const float*)d_in[15];
  const float* aa_qkv_w = (const float*)d_in[16];
  const float* aa_relpos= (const float*)d_in[17];
  const float* aa_out_w = (const float*)d_in[18];
  const float* aa_out_b = (const float*)d_in[19];
  const float* ad_dir_w = (const float*)d_in[20];
  const float* ad_ap_w1 = (const float*)d_in[21];
  const float* ad_ap_b1 = (const float*)d_in[22];
  const float* ad_ap_w2 = (const float*)d_in[23];
  const float* ad_ap_b2 = (const float*)d_in[24];
  const float* ad_proj_w= (const float*)d_in[25];
  const float* ad_proj_b= (const float*)d_in[26];
  const float* gate_w   = (const float*)d_in[27];
  const float* gate_b   = (const float*)d_in[28];
  const float* proj_w   = (const float*)d_in[29];
  const float* proj_b   = (const float*)d_in[30];

  char* ws = (char*)d_ws;
  float* normed    = (float*)(ws + 0);
  float* xr        = (float*)(ws + 1605632);
  float* h1_g      = (float*)(ws + 3211264);
  float* lnm       = (float*)(ws + 3420160);
  float* lnr       = (float*)(ws + 3426560);
  float* spatial   = (float*)(ws + 4816896);
  float* rotf      = (float*)(ws + 6422528);
  float* anglef    = (float*)(ws + 8028160);
  float* adaptf    = (float*)(ws + 9633792);
  float* r0        = (float*)(ws + 12845056);
  float* gap       = (float*)(ws + 14450688);
  float* aw        = (float*)(ws + 14483456);
  float* gates     = (float*)(ws + 14485504);
  float* ra_qkv    = (float*)(ws + 14510592);
  float* aa_qkv    = (float*)(ws + 19327488);
  float* aa_o      = (float*)(ws + 28961280);
  float* partial   = (float*)(ws + 33778176);   // 12,845,056 B
  u16*   xim       = (u16*)  (ws + 46623232);   // 20,070,400 B
  u8*    weff      = (u8*)   (ws + 66693632);   // 52,428,800 B (fp8)

  float* out = (float*)d_out;

  k_prep1<<<dim3(8, 32), 256, 0, stream>>>(x, gn_g, gn_b, ra_gn_g, ra_gn_b, normed, xr, gap);
  k_pre2<<<dim3(15, 32), 256, 0, stream>>>(x, normed, gate_w, gate_b,
                                           sa_w1, sa_b1, ad_ap_w1, ad_ap_b1, ad_ap_w2, ad_ap_b2,
                                           gap, gates, lnm, lnr, h1_g, aw);
  k_mega1<<<dim3(5472), 256, 0, stream>>>(ad_dir_w, aw, weff,
                                          ra_qkv_w, aa_qkv_w, xr, normed,
                                          lnm, lnr, aa_ln_g, aa_ln_b, ra_qkv, aa_qkv,
                                          xim);
  k_mega2<<<dim3(1280), 256, 0, stream>>>(weff, xim, partial,
                                          ra_qkv, aa_qkv, aa_relpos, r0, aa_o,
                                          normed, h1_g, sa_w2, sa_b2, sa_gn_g, sa_gn_b, spatial);
  k_proj3<<<dim3(24, 32), 256, 0, stream>>>(ra_proj_w, ra_proj_b, r0,
                                            aa_out_w, aa_out_b, aa_o,
                                            ad_proj_w, ad_proj_b, partial,
                                            normed, rotf, anglef, adaptf);
  k_final<<<dim3(8, 32), 256, 0, stream>>>(proj_w, proj_b, spatial, rotf, anglef, adaptf,
                                           gates, x, out);
}

// Round 19
// 247.982 us; speedup vs baseline: 1.0841x; 1.0011x over previous
//
#include <hip/hip_runtime.h>

#define EPS 1e-5f
typedef unsigned char u8;
typedef unsigned short u16;
typedef unsigned int u32;
typedef float f32x2 __attribute__((ext_vector_type(2)));
typedef float f32x4 __attribute__((ext_vector_type(4)));
typedef short bf16x8 __attribute__((ext_vector_type(8)));
typedef unsigned int u32x2 __attribute__((ext_vector_type(2)));

__device__ __forceinline__ float bf2f(u16 h){
  return __uint_as_float(((u32)h) << 16);
}
// software RNE f32->bf16 (scalar u16 stores only)
__device__ __forceinline__ u16 f2bf(float f){
  u32 u = __float_as_uint(f);
  u += 0x7fffu + ((u >> 16) & 1u);
  return (u16)(u >> 16);
}
// HW packed f32x2 -> bf16x2 (lo in [15:0], hi in [31:16])
__device__ __forceinline__ u32 pk2(float lo, float hi){
  u32 r;
  asm("v_cvt_pk_bf16_f32 %0, %1, %2" : "=v"(r) : "v"(lo), "v"(hi));
  return r;
}
union BF8 { bf16x8 v; u32 u[4]; };

// fp8x8 (packed in u32x2) -> bf16x8 via HW cvt (8 VALU ops total)
__device__ __forceinline__ bf16x8 fp8_to_bf16x8(u32x2 a){
  f32x2 f01 = __builtin_amdgcn_cvt_pk_f32_fp8(a.x, false);
  f32x2 f23 = __builtin_amdgcn_cvt_pk_f32_fp8(a.x, true);
  f32x2 f45 = __builtin_amdgcn_cvt_pk_f32_fp8(a.y, false);
  f32x2 f67 = __builtin_amdgcn_cvt_pk_f32_fp8(a.y, true);
  BF8 r;
  r.u[0] = pk2(f01.x, f01.y); r.u[1] = pk2(f23.x, f23.y);
  r.u[2] = pk2(f45.x, f45.y); r.u[3] = pk2(f67.x, f67.y);
  return r.v;
}

// ---------------------------------------------------------------------------
// k_prep1: GN(x)->normed, GN(normed)->xr, gap. grid(8,32).
// ---------------------------------------------------------------------------
__global__ __launch_bounds__(256) void k_prep1(
    const float* __restrict__ x, const float* __restrict__ gn_g, const float* __restrict__ gn_b,
    const float* __restrict__ ra_g, const float* __restrict__ ra_b,
    float* __restrict__ normed, float* __restrict__ xr, float* __restrict__ gap)
{
  int ch = blockIdx.x, b = blockIdx.y;
  int c0 = ch * 32;
  __shared__ float xs[1568], ns[1568];
  const float* xb = x + ((size_t)b * 256 + c0) * 49;
  for (int i = threadIdx.x; i < 1568; i += 256) xs[i] = xb[i];
  __syncthreads();
  int wv = threadIdx.x >> 6, lane = threadIdx.x & 63;
  const float* gsrc = xs + wv * 392;
  float* ndst = ns + wv * 392;
  float s = 0.f, ss = 0.f;
  for (int i = lane; i < 392; i += 64){ float v = gsrc[i]; s += v; ss += v * v; }
  for (int off = 32; off; off >>= 1){ s += __shfl_down(s, off); ss += __shfl_down(ss, off); }
  s = __shfl(s, 0); ss = __shfl(ss, 0);
  float m = s / 392.f, rs = rsqrtf(ss / 392.f - m * m + EPS);
  for (int i = lane; i < 392; i += 64){
    int c = c0 + wv * 8 + i / 49;
    ndst[i] = (gsrc[i] - m) * rs * gn_g[c] + gn_b[c];
  }
  __syncthreads();
  float* nb = normed + ((size_t)b * 256 + c0) * 49;
  for (int i = threadIdx.x; i < 1568; i += 256) nb[i] = ns[i];
  if (threadIdx.x < 32){
    float g2 = 0.f; const float* rp = ns + threadIdx.x * 49;
    for (int p = 0; p < 49; p++) g2 += rp[p];
    gap[(size_t)b * 256 + c0 + threadIdx.x] = g2 * (1.f / 49.f);
  }
  s = 0.f; ss = 0.f;
  for (int i = lane; i < 392; i += 64){ float v = ndst[i]; s += v; ss += v * v; }
  for (int off = 32; off; off >>= 1){ s += __shfl_down(s, off); ss += __shfl_down(ss, off); }
  s = __shfl(s, 0); ss = __shfl(ss, 0);
  m = s / 392.f; rs = rsqrtf(ss / 392.f - m * m + EPS);
  float* xrb = xr + ((size_t)b * 256 + c0) * 49;
  for (int i = lane; i < 392; i += 64){
    int c = c0 + wv * 8 + i / 49;
    xrb[wv * 392 + i] = (ndst[i] - m) * rs * ra_g[c] + ra_b[c];
  }
}

// ---------------------------------------------------------------------------
// dev_pos / dev_h1aw  (merged into k_pre2)
// ---------------------------------------------------------------------------
__device__ void dev_pos(
    const float* __restrict__ x, const float* __restrict__ normed,
    const float* __restrict__ gate_w, const float* __restrict__ gate_b,
    float* __restrict__ gates_g, float* __restrict__ lnm_g, float* __restrict__ lnr_g,
    int pc, int b, float* sm)
{
  float* gw = sm;  // 1024
  for (int i = threadIdx.x; i < 1024; i += 256) gw[i] = gate_w[i];
  __syncthreads();
  int wv = threadIdx.x >> 6, lane = threadIdx.x & 63;
  for (int pi = wv; pi < 7; pi += 4){
    int p = pc * 7 + pi;
    const float* nb = normed + (size_t)b * 12544 + p;
    const float* xb = x + (size_t)b * 12544 + p;
    float s = 0.f, ss = 0.f, g0 = 0.f, g1 = 0.f, g2 = 0.f, g3 = 0.f;
    for (int c = lane; c < 256; c += 64){
      float nv = nb[c * 49];
      float xv = xb[c * 49];
      s += nv; ss += nv * nv;
      g0 += xv * gw[c]; g1 += xv * gw[256 + c];
      g2 += xv * gw[512 + c]; g3 += xv * gw[768 + c];
    }
    for (int off = 32; off; off >>= 1){
      s += __shfl_down(s, off); ss += __shfl_down(ss, off);
      g0 += __shfl_down(g0, off); g1 += __shfl_down(g1, off);
      g2 += __shfl_down(g2, off); g3 += __shfl_down(g3, off);
    }
    if (lane == 0){
      float mu = s / 256.f;
      lnm_g[b * 49 + p] = mu;
      lnr_g[b * 49 + p] = rsqrtf(ss / 256.f - mu * mu + EPS);
      g0 += gate_b[0]; g1 += gate_b[1]; g2 += gate_b[2]; g3 += gate_b[3];
      float mx = fmaxf(fmaxf(g0, g1), fmaxf(g2, g3));
      float e0 = __expf(g0 - mx), e1 = __expf(g1 - mx), e2 = __expf(g2 - mx), e3 = __expf(g3 - mx);
      float inv = 1.f / (e0 + e1 + e2 + e3);
      float* gg = gates_g + (size_t)b * 196 + p;
      gg[0] = e0 * inv; gg[49] = e1 * inv; gg[98] = e2 * inv; gg[147] = e3 * inv;
    }
  }
}

__device__ void dev_h1aw(
    const float* __restrict__ normed, const float* __restrict__ sa_w1, const float* __restrict__ sa_b1,
    const float* __restrict__ ap_w1, const float* __restrict__ ap_b1,
    const float* __restrict__ ap_w2, const float* __restrict__ ap_b2,
    const float* __restrict__ gap_g,
    float* __restrict__ h1_g, float* __restrict__ aw_g,
    int xb2, int b, float* sm)
{
  int t = threadIdx.x;
  if (xb2 == 7){
    float* gaps = sm; float* h = sm + 256; float* lg = sm + 384;
    gaps[t] = gap_g[b * 256 + t];
    __syncthreads();
    if (t < 128){
      float s = ap_b1[t];
      const float* wr = ap_w1 + t * 256;
      #pragma unroll 4
      for (int c = 0; c < 256; c++) s += gaps[c] * wr[c];
      h[t] = fmaxf(s, 0.f);
    }
    __syncthreads();
    if (t < 16){
      float s = ap_b2[t];
      const float* wr = ap_w2 + t * 128;
      #pragma unroll 4
      for (int o = 0; o < 128; o++) s += h[o] * wr[o];
      lg[t] = s;
    }
    __syncthreads();
    if (t == 0){
      float mx = -1e30f;
      for (int k = 0; k < 16; k++) mx = fmaxf(mx, lg[k]);
      float e[16], smm = 0.f;
      for (int k = 0; k < 16; k++){ e[k] = __expf(lg[k] - mx); smm += e[k]; }
      float inv = 1.f / smm;
      for (int k = 0; k < 16; k++) aw_g[b * 16 + k] = e[k] * inv;
    }
    return;
  }
  float* w1t = sm;            // 8448
  float* ns2 = sm + 8448;     // 1792
  int p0 = xb2 * 7;
  for (int i = t; i < 8192; i += 256){
    int o = i >> 8, c = i & 255;
    w1t[c * 33 + o] = sa_w1[i];
  }
  for (int i = t; i < 1792; i += 256){
    int c = i / 7, pl = i - c * 7;
    ns2[i] = normed[(size_t)b * 12544 + c * 49 + p0 + pl];
  }
  __syncthreads();
  if (t < 224){
    int pl = t >> 5, o = t & 31;
    float s = sa_b1[o];
    #pragma unroll 8
    for (int c = 0; c < 256; c++) s += ns2[c * 7 + pl] * w1t[c * 33 + o];
    h1_g[(size_t)b * 1568 + (p0 + pl) * 32 + o] = fmaxf(s, 0.f);
  }
}

__global__ __launch_bounds__(256) void k_pre2(
    const float* __restrict__ x, const float* __restrict__ normed,
    const float* __restrict__ gate_w, const float* __restrict__ gate_b,
    const float* __restrict__ sa_w1, const float* __restrict__ sa_b1,
    const float* __restrict__ ap_w1, const float* __restrict__ ap_b1,
    const float* __restrict__ ap_w2, const float* __restrict__ ap_b2,
    const float* __restrict__ gap_g,
    float* __restrict__ gates_g, float* __restrict__ lnm_g, float* __restrict__ lnr_g,
    float* __restrict__ h1_g, float* __restrict__ aw_g)
{
  __shared__ float sm[10240];
  int bx = blockIdx.x, b = blockIdx.y;
  if (bx < 7)
    dev_pos(x, normed, gate_w, gate_b, gates_g, lnm_g, lnr_g, bx, b, sm);
  else
    dev_h1aw(normed, sa_w1, sa_b1, ap_w1, ap_b1, ap_w2, ap_b2, gap_g, h1_g, aw_g, bx - 7, b, sm);
}

// ---------------------------------------------------------------------------
// device pieces
// ---------------------------------------------------------------------------
__device__ void dev_spatial(
    const float* __restrict__ normed, const float* __restrict__ h1_g,
    const float* __restrict__ sa_w2, const float* __restrict__ sa_b2,
    const float* __restrict__ sa_g, const float* __restrict__ sa_bb,
    float* __restrict__ spat_g, int gc, int b, float* sm)
{
  float* h1s = sm;           // 1617
  float* w2s = sm + 1617;    // 1024
  int t = threadIdx.x;
  for (int i = t; i < 1568; i += 256){
    int p = i >> 5, o = i & 31;
    h1s[p * 33 + o] = h1_g[(size_t)b * 1568 + i];
  }
  for (int i = t; i < 1024; i += 256) w2s[i] = sa_w2[gc * 1024 + i];
  __syncthreads();
  int wv = t >> 6, lane = t & 63;
  int cg0 = wv * 8;
  const float* nb = normed + (size_t)b * 12544 + (gc * 32 + cg0) * 49;
  float tmp[7];
  float s = 0.f, ss = 0.f;
  #pragma unroll
  for (int j = 0; j < 7; j++){
    int i = lane + 64 * j;
    float v = 0.f;
    if (i < 392){
      int c = i / 49;
      const float* wr = w2s + (cg0 + c) * 32;
      const float* hp = h1s + (i - c * 49) * 33;
      float d = sa_b2[gc * 32 + cg0 + c];
      #pragma unroll
      for (int o = 0; o < 32; o++) d += hp[o] * wr[o];
      v = nb[i] * (1.f + 1.f / (1.f + __expf(-d)));
      s += v; ss += v * v;
    }
    tmp[j] = v;
  }
  for (int off = 32; off; off >>= 1){ s += __shfl_down(s, off); ss += __shfl_down(ss, off); }
  s = __shfl(s, 0); ss = __shfl(ss, 0);
  float m = s / 392.f, rs = rsqrtf(ss / 392.f - m * m + EPS);
  float* sb = spat_g + (size_t)b * 12544 + (gc * 32 + cg0) * 49;
  #pragma unroll
  for (int j = 0; j < 7; j++){
    int i = lane + 64 * j;
    if (i < 392){
      int c = gc * 32 + cg0 + i / 49;
      sb[i] = (tmp[j] - m) * rs * sa_g[c] + sa_bb[c];
    }
  }
}

// weff: fp8 e4m3, pre-scaled x16 (decode side folds 1/16 into xim).
__device__ void dev_weff(
    const float* __restrict__ W, const float* __restrict__ aw, u8* __restrict__ weff, int bx)
{
  const size_t t = ((size_t)bx * 256 + threadIdx.x) * 4;
  float4 A[16];
  #pragma unroll
  for (int k = 0; k < 16; k++) A[k] = *(const float4*)(W + (size_t)k * 1638400 + t);
  #pragma unroll 1
  for (int b = 0; b < 32; b++){
    float s0 = 0.f, s1 = 0.f, s2 = 0.f, s3 = 0.f;
    #pragma unroll
    for (int k = 0; k < 16; k++){
      float a = aw[b * 16 + k];
      s0 += a * A[k].x; s1 += a * A[k].y; s2 += a * A[k].z; s3 += a * A[k].w;
    }
    int pk = __builtin_amdgcn_cvt_pk_fp8_f32(s0 * 16.f, s1 * 16.f, 0, false);
    pk = __builtin_amdgcn_cvt_pk_fp8_f32(s2 * 16.f, s3 * 16.f, pk, true);
    __builtin_nontemporal_store((u32)pk, (u32*)(weff + (size_t)b * 1638400 + t));
  }
}

// im2col: xim = bf16(normed/16); zero outside image.
__device__ void dev_im2col(
    const float* __restrict__ normed, u16* __restrict__ xim, int p, int b, float* sm)
{
  u16* row = (u16*)sm;  // 6400 u16
  int ci = threadIdx.x;
  int py = p / 7, px = p - py * 7;
  const float* nb = normed + (size_t)b * 12544 + ci * 49;
  u16* rp = row + ci * 25;
  #pragma unroll
  for (int sy = 0; sy < 5; sy++){
    int iy = py + sy - 2;
    #pragma unroll
    for (int sx = 0; sx < 5; sx++){
      int ix = px + sx - 2;
      float v = (iy >= 0 && iy < 7 && ix >= 0 && ix < 7) ? nb[iy * 7 + ix] * 0.0625f : 0.f;
      rp[sy * 5 + sx] = f2bf(v);
    }
  }
  __syncthreads();
  const u32* rs = (const u32*)row;
  u32* od = (u32*)(xim + (size_t)(b * 49 + p) * 6400);
  for (int i = threadIdx.x; i < 3200; i += 256) od[i] = rs[i];
}

// mfma_gemm_dev: per-wave 32m x 16p tile; optional LN-fused act, optional
// 8-way partial-sum act (part8 != nullptr reads Sum_kp partial instead).
__device__ __forceinline__ void mfma_gemm_dev(
    const float* __restrict__ W, const float* __restrict__ bias,
    const float* __restrict__ act, const float* __restrict__ res,
    float* __restrict__ out, int M, int K, int m0blk, int p0, int b,
    const float* __restrict__ lnm, const float* __restrict__ lnr,
    const float* __restrict__ lng, const float* __restrict__ lnb,
    const float* __restrict__ part8 = nullptr)
{
  int wv = threadIdx.x >> 6, lane = threadIdx.x & 63;
  int lo = lane & 15, hi = lane >> 4;
  int m0 = m0blk + wv * 32;
  int p = p0 + lo;
  bool pok = p < 49;
  const float* ab = act + (size_t)b * K * 49;
  float lm = 0.f, lr = 0.f;
  if (lng && pok){ lm = lnm[p]; lr = lnr[p]; }
  f32x4 acc0 = {0.f, 0.f, 0.f, 0.f};
  f32x4 acc1 = {0.f, 0.f, 0.f, 0.f};
  const float* wr0 = W + (size_t)(m0 + lo) * K + hi * 8;
  const float* wr1 = W + (size_t)(m0 + 16 + lo) * K + hi * 8;
  for (int k0 = 0; k0 < K; k0 += 32){
    int kb = k0 + hi * 8;
    float4 a0lo = *(const float4*)(wr0 + k0);
    float4 a0hi = *(const float4*)(wr0 + k0 + 4);
    float4 a1lo = *(const float4*)(wr1 + k0);
    float4 a1hi = *(const float4*)(wr1 + k0 + 4);
    float bv[8];
    if (pok){
      if (part8){
        const float* pp = part8 + (size_t)b * 12544 + (size_t)kb * 49 + p;
        #pragma unroll
        for (int i = 0; i < 8; i++){
          float s = 0.f;
          #pragma unroll
          for (int kp = 0; kp < 8; kp++) s += pp[(size_t)kp * 401408 + i * 49];
          bv[i] = s;
        }
      } else {
        const float* ap = ab + (size_t)kb * 49 + p;
        #pragma unroll
        for (int i = 0; i < 8; i++) bv[i] = ap[i * 49];
        if (lng){
          #pragma unroll
          for (int i = 0; i < 8; i++) bv[i] = (bv[i] - lm) * lr * lng[kb + i] + lnb[kb + i];
        }
      }
    } else {
      #pragma unroll
      for (int i = 0; i < 8; i++) bv[i] = 0.f;
    }
    BF8 A0, A1, B;
    A0.u[0] = pk2(a0lo.x, a0lo.y); A0.u[1] = pk2(a0lo.z, a0lo.w);
    A0.u[2] = pk2(a0hi.x, a0hi.y); A0.u[3] = pk2(a0hi.z, a0hi.w);
    A1.u[0] = pk2(a1lo.x, a1lo.y); A1.u[1] = pk2(a1lo.z, a1lo.w);
    A1.u[2] = pk2(a1hi.x, a1hi.y); A1.u[3] = pk2(a1hi.z, a1hi.w);
    B.u[0] = pk2(bv[0], bv[1]); B.u[1] = pk2(bv[2], bv[3]);
    B.u[2] = pk2(bv[4], bv[5]); B.u[3] = pk2(bv[6], bv[7]);
    acc0 = __builtin_amdgcn_mfma_f32_16x16x32_bf16(A0.v, B.v, acc0, 0, 0, 0);
    acc1 = __builtin_amdgcn_mfma_f32_16x16x32_bf16(A1.v, B.v, acc1, 0, 0, 0);
  }
  if (pok){
    #pragma unroll
    for (int r = 0; r < 4; r++){
      int m = m0 + hi * 4 + r;
      size_t idx = ((size_t)b * M + m) * 49 + p;
      float v = acc0[r] + (bias ? bias[m] : 0.f);
      if (res) v += res[idx];
      out[idx] = v;
      int m2 = m + 16;
      size_t idx2 = idx + 16 * 49;
      float v2 = acc1[r] + (bias ? bias[m2] : 0.f);
      if (res) v2 += res[idx2];
      out[idx2] = v2;
    }
  }
}

__device__ void dev_conv(
    const u8* __restrict__ weff, const u16* __restrict__ xim, float* __restrict__ partial,
    int bx, int b)
{
  int mblk = bx >> 3, kp = bx & 7;
  int wv = threadIdx.x >> 6, lane = threadIdx.x & 63;
  int lo = lane & 15, hi = lane >> 4;
  int co0 = mblk * 128 + wv * 32;
  const u8* wr0 = weff + (size_t)b * 1638400 + (size_t)(co0 + lo) * 6400 + kp * 800 + hi * 8;
  const u8* wr1 = wr0 + 16 * 6400;
  const u16* xb = xim + (size_t)b * 313600 + (size_t)lo * 6400 + kp * 800 + hi * 8;
  f32x4 acc[2][4];
  #pragma unroll
  for (int mi = 0; mi < 2; mi++)
    #pragma unroll
    for (int pi = 0; pi < 4; pi++) acc[mi][pi] = (f32x4){0.f, 0.f, 0.f, 0.f};
  #pragma unroll 1
  for (int ks = 0; ks < 25; ks++){
    int k0 = ks * 32;
    u32x2 a0p = __builtin_nontemporal_load((const u32x2*)(wr0 + k0));
    u32x2 a1p = __builtin_nontemporal_load((const u32x2*)(wr1 + k0));
    bf16x8 A0 = fp8_to_bf16x8(a0p);
    bf16x8 A1 = fp8_to_bf16x8(a1p);
    bf16x8 B0 = *(const bf16x8*)(xb + k0);
    bf16x8 B1 = *(const bf16x8*)(xb + 16 * 6400 + k0);
    bf16x8 B2 = *(const bf16x8*)(xb + 32 * 6400 + k0);
    bf16x8 B3 = *(const bf16x8*)(xb + 48 * 6400 + k0);
    acc[0][0] = __builtin_amdgcn_mfma_f32_16x16x32_bf16(A0, B0, acc[0][0], 0, 0, 0);
    acc[0][1] = __builtin_amdgcn_mfma_f32_16x16x32_bf16(A0, B1, acc[0][1], 0, 0, 0);
    acc[0][2] = __builtin_amdgcn_mfma_f32_16x16x32_bf16(A0, B2, acc[0][2], 0, 0, 0);
    acc[0][3] = __builtin_amdgcn_mfma_f32_16x16x32_bf16(A0, B3, acc[0][3], 0, 0, 0);
    acc[1][0] = __builtin_amdgcn_mfma_f32_16x16x32_bf16(A1, B0, acc[1][0], 0, 0, 0);
    acc[1][1] = __builtin_amdgcn_mfma_f32_16x16x32_bf16(A1, B1, acc[1][1], 0, 0, 0);
    acc[1][2] = __builtin_amdgcn_mfma_f32_16x16x32_bf16(A1, B2, acc[1][2], 0, 0, 0);
    acc[1][3] = __builtin_amdgcn_mfma_f32_16x16x32_bf16(A1, B3, acc[1][3], 0, 0, 0);
  }
  float* pb = partial + ((size_t)kp * 32 + b) * 12544;
  #pragma unroll
  for (int mi = 0; mi < 2; mi++){
    #pragma unroll
    for (int pi = 0; pi < 4; pi++){
      int p = pi * 16 + lo;
      if (p < 49){
        #pragma unroll
        for (int r = 0; r < 4; r++){
          int co = co0 + mi * 16 + hi * 4 + r;
          pb[co * 49 + p] = acc[mi][pi][r];
        }
      }
    }
  }
}

__device__ __forceinline__ void softmax_rows(float* sc, int tid)
{
  int r = tid >> 2, q = tid & 3;
  if (r < 49){
    float* row = sc + r * 52;
    float mx = -1e30f;
    for (int j = q; j < 49; j += 4) mx = fmaxf(mx, row[j]);
    mx = fmaxf(mx, __shfl_xor(mx, 1));
    mx = fmaxf(mx, __shfl_xor(mx, 2));
    float sm = 0.f;
    for (int j = q; j < 49; j += 4){ float e = __expf(row[j] - mx); row[j] = e; sm += e; }
    sm += __shfl_xor(sm, 1);
    sm += __shfl_xor(sm, 2);
    float inv = 1.f / sm;
    for (int j = q; j < 49; j += 4) row[j] *= inv;
  }
}

__device__ void dev_attn(
    const float* __restrict__ ra_qkv, const float* __restrict__ aa_qkv,
    const float* __restrict__ relpos,
    float* __restrict__ r0, float* __restrict__ ao,
    int xb2, int b, float* sm)
{
  if (xb2 < 8){
    int hd = xb2;
    float* qs = sm; float* ks = sm + 1617; float* vs = sm + 3234; float* sc = sm + 4851;
    const float* base = ra_qkv + (size_t)b * 768 * 49;
    for (int i = threadIdx.x; i < 1568; i += 256){
      int d = i / 49, tok = i - d * 49;
      qs[tok * 33 + d] = base[(hd * 32 + d) * 49 + tok];
      ks[tok * 33 + d] = base[(256 + hd * 32 + d) * 49 + tok];
      vs[tok * 33 + d] = base[(512 + hd * 32 + d) * 49 + tok];
    }
    __syncthreads();
    const float scale = 0.17677669529663687f;
    for (int it = threadIdx.x; it < 2401; it += 256){
      int i = it / 49, j = it - i * 49;
      float s = 0.f;
      #pragma unroll
      for (int d = 0; d < 32; d++) s += qs[i * 33 + d] * ks[j * 33 + d];
      sc[i * 52 + j] = s * scale;
    }
    __syncthreads();
    softmax_rows(sc, threadIdx.x);
    __syncthreads();
    for (int it = threadIdx.x; it < 1568; it += 256){
      int d = it / 49, i = it - d * 49;
      float o = 0.f;
      for (int j = 0; j < 49; j++) o += sc[i * 52 + j] * vs[j * 33 + d];
      r0[((size_t)b * 256 + hd * 32 + d) * 49 + i] = o;
    }
  } else {
    int hd = xb2 - 8;
    float* qs = sm; float* ks = sm + 3185; float* vs = sm + 6370; float* sc = sm + 9555;
    const float* base = aa_qkv + (size_t)b * 1536 * 49;
    for (int i = threadIdx.x; i < 3136; i += 256){
      int d = i / 49, tok = i - d * 49;
      qs[tok * 65 + d] = base[(hd * 64 + d) * 49 + tok];
      ks[tok * 65 + d] = base[(512 + hd * 64 + d) * 49 + tok];
      vs[tok * 65 + d] = base[(1024 + hd * 64 + d) * 49 + tok];
    }
    __syncthreads();
    for (int it = threadIdx.x; it < 2401; it += 256){
      int i = it / 49, j = it - i * 49;
      float s = 0.f;
      #pragma unroll
      for (int d = 0; d < 64; d++) s += qs[i * 65 + d] * ks[j * 65 + d];
      int dy = j / 7 - i / 7 + 6, dx = j % 7 - i % 7 + 6;
      sc[i * 52 + j] = s * 0.125f + relpos[(dy * 13 + dx) * 8 + hd];
    }
    __syncthreads();
    softmax_rows(sc, threadIdx.x);
    __syncthreads();
    for (int it = threadIdx.x; it < 3136; it += 256){
      int d = it / 49, i = it - d * 49;
      float o = 0.f;
      for (int j = 0; j < 49; j++) o += sc[i * 52 + j] * vs[j * 65 + d];
      ao[((size_t)b * 512 + hd * 64 + d) * 49 + i] = o;
    }
  }
}

// ---------------------------------------------------------------------------
// k_mega1: 5472 blocks scrambled (*2003 mod 5472):
// id<1600 weff | <3904 qkv | else im2col
// ---------------------------------------------------------------------------
__global__ __launch_bounds__(256) void k_mega1(
    const float* __restrict__ ad_dir_w, const float* __restrict__ aw, u8* __restrict__ weff,
    const float* __restrict__ ra_w, const float* __restrict__ aa_w,
    const float* __restrict__ xr, const float* __restrict__ normed,
    const float* __restrict__ lnm, const float* __restrict__ lnr,
    const float* __restrict__ ln_g, const float* __restrict__ ln_b,
    float* __restrict__ ra_qkv, float* __restrict__ aa_qkv,
    u16* __restrict__ xim)
{
  __shared__ float sm[3300];
  int id = (int)(((long long)blockIdx.x * 2003) % 5472);
  if (id < 1600){
    dev_weff(ad_dir_w, aw, weff, id);
  } else if (id < 3904){
    int q = id - 1600;
    int bx = q % 72, b = q / 72;
    if (bx < 24){
      int m0 = (bx >> 2) * 128, p0 = (bx & 3) * 16;
      mfma_gemm_dev(ra_w, nullptr, xr, nullptr, ra_qkv, 768, 256, m0, p0, b,
                    nullptr, nullptr, nullptr, nullptr);
    } else {
      int bx2 = bx - 24;
      int m0 = (bx2 >> 2) * 128, p0 = (bx2 & 3) * 16;
      mfma_gemm_dev(aa_w, nullptr, normed, nullptr, aa_qkv, 1536, 256, m0, p0, b,
                    lnm + b * 49, lnr + b * 49, ln_g, ln_b);
    }
  } else {
    int q = id - 3904;
    dev_im2col(normed, xim, q % 49, q / 49, sm);
  }
}

// ---------------------------------------------------------------------------
// k_mega2: 1280 blocks scrambled (*521 mod 1280):
// id<512 conv | <1024 attn | else spatial
// ---------------------------------------------------------------------------
__global__ __launch_bounds__(256) void k_mega2(
    const u8* __restrict__ weff, const u16* __restrict__ xim, float* __restrict__ partial,
    const float* __restrict__ ra_qkv, const float* __restrict__ aa_qkv,
    const float* __restrict__ relpos, float* __restrict__ r0, float* __restrict__ ao,
    const float* __restrict__ normed, const float* __restrict__ h1_g,
    const float* __restrict__ sa_w2, const float* __restrict__ sa_b2,
    const float* __restrict__ sa_g, const float* __restrict__ sa_bb,
    float* __restrict__ spat_g)
{
  __shared__ float sm[12103];
  int id = (int)(((long long)blockIdx.x * 521) % 1280);
  if (id < 512){
    dev_conv(weff, xim, partial, id % 16, id / 16);
  } else if (id < 1024){
    int q = id - 512;
    dev_attn(ra_qkv, aa_qkv, relpos, r0, ao, q % 16, q / 16, sm);
  } else {
    int q = id - 1024;
    dev_spatial(normed, h1_g, sa_w2, sa_b2, sa_g, sa_bb, spat_g, q % 8, q / 8, sm);
  }
}

// ---------------------------------------------------------------------------
// k_proj3: bx<8 ra_proj, <16 aa_out (K=512), else ad_proj (act = 8-way
// partial sum, inline reduce)
// ---------------------------------------------------------------------------
__global__ __launch_bounds__(256) void k_proj3(
    const float* __restrict__ ra_pw, const float* __restrict__ ra_pb, const float* __restrict__ r0,
    const float* __restrict__ aa_ow, const float* __restrict__ aa_ob, const float* __restrict__ aa_o,
    const float* __restrict__ ad_pw, const float* __restrict__ ad_pb, const float* __restrict__ partial,
    const float* __restrict__ normed,
    float* __restrict__ rotf, float* __restrict__ angf, float* __restrict__ adpf)
{
  int bx = blockIdx.x, b = blockIdx.y;
  if (bx < 8){
    int m0 = (bx >> 2) * 128, p0 = (bx & 3) * 16;
    mfma_gemm_dev(ra_pw, ra_pb, r0, normed, rotf, 256, 256, m0, p0, b,
                  nullptr, nullptr, nullptr, nullptr);
  } else if (bx < 16){
    int bx2 = bx - 8;
    int m0 = (bx2 >> 2) * 128, p0 = (bx2 & 3) * 16;
    mfma_gemm_dev(aa_ow, aa_ob, aa_o, normed, angf, 256, 512, m0, p0, b,
                  nullptr, nullptr, nullptr, nullptr);
  } else {
    int bx2 = bx - 16;
    int m0 = (bx2 >> 2) * 128, p0 = (bx2 & 3) * 16;
    mfma_gemm_dev(ad_pw, ad_pb, partial /*unused as act*/, normed, adpf, 256, 256, m0, p0, b,
                  nullptr, nullptr, nullptr, nullptr, partial);
  }
}

// k_final: out = proj_w @ fused + proj_b + x, fused computed on the fly
__global__ __launch_bounds__(256) void k_final(
    const float* __restrict__ proj_w, const float* __restrict__ proj_b,
    const float* __restrict__ spat, const float* __restrict__ rotf,
    const float* __restrict__ angf, const float* __restrict__ adpf,
    const float* __restrict__ gates, const float* __restrict__ x,
    float* __restrict__ out)
{
  int bx = blockIdx.x, b = blockIdx.y;
  int wv = threadIdx.x >> 6, lane = threadIdx.x & 63;
  int lo = lane & 15, hi = lane >> 4;
  int m0 = (bx >> 2) * 128 + wv * 32;
  int p0 = (bx & 3) * 16;
  int p = p0 + lo;
  bool pok = p < 49;
  float g0 = 0.f, g1 = 0.f, g2 = 0.f, g3 = 0.f;
  if (pok){
    const float* g = gates + (size_t)b * 196 + p;
    g0 = g[0]; g1 = g[49]; g2 = g[98]; g3 = g[147];
  }
  size_t boff = (size_t)b * 12544;
  f32x4 acc0 = {0.f, 0.f, 0.f, 0.f};
  f32x4 acc1 = {0.f, 0.f, 0.f, 0.f};
  const float* wr0 = proj_w + (size_t)(m0 + lo) * 256 + hi * 8;
  const float* wr1 = wr0 + 16 * 256;
  for (int k0 = 0; k0 < 256; k0 += 32){
    int kb = k0 + hi * 8;
    float4 a0lo = *(const float4*)(wr0 + k0);
    float4 a0hi = *(const float4*)(wr0 + k0 + 4);
    float4 a1lo = *(const float4*)(wr1 + k0);
    float4 a1hi = *(const float4*)(wr1 + k0 + 4);
    float bv[8];
    if (pok){
      size_t base = boff + (size_t)kb * 49 + p;
      #pragma unroll
      for (int i = 0; i < 8; i++){
        size_t idx = base + (size_t)i * 49;
        bv[i] = spat[idx] * g0 + rotf[idx] * g1 + angf[idx] * g2 + adpf[idx] * g3;
      }
    } else {
      #pragma unroll
      for (int i = 0; i < 8; i++) bv[i] = 0.f;
    }
    BF8 A0, A1, B;
    A0.u[0] = pk2(a0lo.x, a0lo.y); A0.u[1] = pk2(a0lo.z, a0lo.w);
    A0.u[2] = pk2(a0hi.x, a0hi.y); A0.u[3] = pk2(a0hi.z, a0hi.w);
    A1.u[0] = pk2(a1lo.x, a1lo.y); A1.u[1] = pk2(a1lo.z, a1lo.w);
    A1.u[2] = pk2(a1hi.x, a1hi.y); A1.u[3] = pk2(a1hi.z, a1hi.w);
    B.u[0] = pk2(bv[0], bv[1]); B.u[1] = pk2(bv[2], bv[3]);
    B.u[2] = pk2(bv[4], bv[5]); B.u[3] = pk2(bv[6], bv[7]);
    acc0 = __builtin_amdgcn_mfma_f32_16x16x32_bf16(A0.v, B.v, acc0, 0, 0, 0);
    acc1 = __builtin_amdgcn_mfma_f32_16x16x32_bf16(A1.v, B.v, acc1, 0, 0, 0);
  }
  if (pok){
    #pragma unroll
    for (int r = 0; r < 4; r++){
      int m = m0 + hi * 4 + r;
      size_t idx = boff + (size_t)m * 49 + p;
      out[idx] = acc0[r] + proj_b[m] + x[idx];
      int m2 = m + 16;
      size_t idx2 = idx + 16 * 49;
      out[idx2] = acc1[r] + proj_b[m2] + x[idx2];
    }
  }
}

// ---------------------------------------------------------------------------
extern "C" void kernel_launch(void* const* d_in, const int* in_sizes, int n_in,
                              void* d_out, int out_size, void* d_ws, size_t ws_size,
                              hipStream_t stream)
{
  const float* x        = (const float*)d_in[0];
  const float* gn_g     = (const float*)d_in[1];
  const float* gn_b     = (const float*)d_in[2];
  const float* sa_w1    = (const float*)d_in[3];
  const float* sa_b1    = (const float*)d_in[4];
  const float* sa_w2    = (const float*)d_in[5];
  const float* sa_b2    = (const float*)d_in[6];
  const float* sa_gn_g  = (const float*)d_in[7];
  const float* sa_gn_b  = (const float*)d_in[8];
  const float* ra_gn_g  = (const float*)d_in[9];
  const float* ra_gn_b  = (const float*)d_in[10];
  const float* ra_qkv_w = (const float*)d_in[11];
  const float* ra_proj_w= (const float*)d_in[12];
  const float* ra_proj_b= (const float*)d_in[13];
  const float* aa_ln_g  = (const float*)d_in[14];
  const float* aa_ln_b  = (const float*)d_in[15];
  const float* aa_qkv_w = (const float*)d_in[16];
  const float* aa_relpos= (const float*)d_in[17];
  const float* aa_out_w = (const float*)d_in[18];
  const float* aa_out_b = (const float*)d_in[19];
  const float* ad_dir_w = (const float*)d_in[20];
  const float* ad_ap_w1 = (const float*)d_in[21];
  const float* ad_ap_b1 = (const float*)d_in[22];
  const float* ad_ap_w2 = (const float*)d_in[23];
  const float* ad_ap_b2 = (const float*)d_in[24];
  const float* ad_proj_w= (const float*)d_in[25];
  const float* ad_proj_b= (const float*)d_in[26];
  const float* gate_w   = (const float*)d_in[27];
  const float* gate_b   = (const float*)d_in[28];
  const float* proj_w   = (const float*)d_in[29];
  const float* proj_b   = (const float*)d_in[30];

  char* ws = (char*)d_ws;
  float* normed    = (float*)(ws + 0);
  float* xr        = (float*)(ws + 1605632);
  float* h1_g      = (float*)(ws + 3211264);
  float* lnm       = (float*)(ws + 3420160);
  float* lnr       = (float*)(ws + 3426560);
  float* spatial   = (float*)(ws + 4816896);
  float* rotf      = (float*)(ws + 6422528);
  float* anglef    = (float*)(ws + 8028160);
  float* adaptf    = (float*)(ws + 9633792);
  float* r0        = (float*)(ws + 12845056);
  float* gap       = (float*)(ws + 14450688);
  float* aw        = (float*)(ws + 14483456);
  float* gates     = (float*)(ws + 14485504);
  float* ra_qkv    = (float*)(ws + 14510592);
  float* aa_qkv    = (float*)(ws + 19327488);
  float* aa_o      = (float*)(ws + 28961280);
  float* partial   = (float*)(ws + 33778176);   // 12,845,056 B
  u16*   xim       = (u16*)  (ws + 46623232);   // 20,070,400 B
  u8*    weff      = (u8*)   (ws + 66693632);   // 52,428,800 B (fp8)

  float* out = (float*)d_out;

  k_prep1<<<dim3(8, 32), 256, 0, stream>>>(x, gn_g, gn_b, ra_gn_g, ra_gn_b, normed, xr, gap);
  k_pre2<<<dim3(15, 32), 256, 0, stream>>>(x, normed, gate_w, gate_b,
                                           sa_w1, sa_b1, ad_ap_w1, ad_ap_b1, ad_ap_w2, ad_ap_b2,
                                           gap, gates, lnm, lnr, h1_g, aw);
  k_mega1<<<dim3(5472), 256, 0, stream>>>(ad_dir_w, aw, weff,
                                          ra_qkv_w, aa_qkv_w, xr, normed,
                                          lnm, lnr, aa_ln_g, aa_ln_b, ra_qkv, aa_qkv,
                                          xim);
  k_mega2<<<dim3(1280), 256, 0, stream>>>(weff, xim, partial,
                                          ra_qkv, aa_qkv, aa_relpos, r0, aa_o,
                                          normed, h1_g, sa_w2, sa_b2, sa_gn_g, sa_gn_b, spatial);
  k_proj3<<<dim3(24, 32), 256, 0, stream>>>(ra_proj_w, ra_proj_b, r0,
                                            aa_out_w, aa_out_b, aa_o,
                                            ad_proj_w, ad_proj_b, partial,
                                            normed, rotf, anglef, adaptf);
  k_final<<<dim3(8, 32), 256, 0, stream>>>(proj_w, proj_b, spatial, rotf, anglef, adaptf,
                                           gates, x, out);
}